// Round 1
// baseline (1175.433 us; speedup 1.0000x reference)
//
#include <hip/hip_runtime.h>
#include <hip/hip_bf16.h>
#include <cstdint>

namespace {

constexpr int B = 4, N = 300, D = 256;
constexpr int G = 4, PIN = 32, POUT = 128;
constexpr int CG = D / G;                    // 64
constexpr int TOTAL = CG * CG + PIN * POUT;  // 8192
constexpr int BN_TOT = B * N;                // 1200
constexpr int GT = G * TOTAL;                // 32768

// ---- bf16 helpers (bit-level, RNE) ----
__device__ __forceinline__ float bf2f(unsigned short u) {
  union { unsigned int i; float f; } x; x.i = ((unsigned int)u) << 16; return x.f;
}
__device__ __forceinline__ unsigned short f2bf(float f) {
  union { float f; unsigned int i; } x; x.f = f;
  unsigned int r = x.i + 0x7fffu + ((x.i >> 16) & 1u);
  return (unsigned short)(r >> 16);
}

// block(256) reduction of two values (sum, sumsq)
__device__ __forceinline__ void breduce2(float& a, float& b, volatile float* red) {
  __syncthreads();  // protect red reuse across sequential calls
  #pragma unroll
  for (int off = 32; off; off >>= 1) {
    a += __shfl_down(a, off, 64);
    b += __shfl_down(b, off, 64);
  }
  int t = threadIdx.x;
  if ((t & 63) == 0) { red[t >> 6] = a; red[4 + (t >> 6)] = b; }
  __syncthreads();
  a = red[0] + red[1] + red[2] + red[3];
  b = red[4] + red[5] + red[6] + red[7];
}

// ---------------- kernel 1: offset GEMM + bilinear sampling ----------------
// grid = 1200 blocks (one per (b,n)), 256 threads.
// thread t -> point j = t>>1 (0..127), channel half = t&1 (32 channels).
__global__ __launch_bounds__(256) void k_sample(
    const float* __restrict__ qf, const float* __restrict__ roi,
    const float* __restrict__ off_w, const float* __restrict__ off_b,
    const float* __restrict__ f0, const float* __restrict__ f1,
    const float* __restrict__ f2, const float* __restrict__ f3,
    float* __restrict__ sampled) {
  int bn = blockIdx.x;
  int bb = bn / N;
  int t = threadIdx.x;
  __shared__ float q[D];
  __shared__ float off[G * PIN * 3];  // 384
  q[t] = qf[(size_t)bn * D + t];
  __syncthreads();
  for (int col = t; col < G * PIN * 3; col += 256) {
    float acc = off_b[col];
    #pragma unroll 4
    for (int d = 0; d < D; ++d) acc += q[d] * off_w[d * (G * PIN * 3) + col];
    off[col] = acc;
  }
  __syncthreads();

  float cx = roi[bn * 4 + 0], cy = roi[bn * 4 + 1];
  float z = roi[bn * 4 + 2], r = roi[bn * 4 + 3];
  float scale = exp2f(z);
  float rw = scale * exp2f(-0.5f * r);
  float rh = scale * exp2f(0.5f * r);

  int j = t >> 1;
  int half = t & 1;
  int g = j >> 5, p = j & 31;
  float sx = cx + off[j * 3 + 0] * rw;
  float sy = cy + off[j * 3 + 1] * rh;
  float sz = z + off[j * 3 + 2];

  // softmax over 4 levels of -((sz-3)-l)^2 / 2
  float lw[4];
  {
    float m = -1e30f;
    #pragma unroll
    for (int l = 0; l < 4; ++l) {
      float dlt = sz - 3.0f - (float)l;
      lw[l] = -dlt * dlt * 0.5f;
      m = fmaxf(m, lw[l]);
    }
    float s = 0.f;
    #pragma unroll
    for (int l = 0; l < 4; ++l) { lw[l] = expf(lw[l] - m); s += lw[l]; }
    float inv = 1.f / s;
    #pragma unroll
    for (int l = 0; l < 4; ++l) lw[l] *= inv;
  }

  const float* fp[4] = {f0, f1, f2, f3};
  const int Wl[4] = {160, 80, 40, 20};
  const int Hl[4] = {100, 50, 25, 13};
  const float sl[4] = {8.f, 16.f, 32.f, 64.f};

  float acc[32];
  #pragma unroll
  for (int c = 0; c < 32; ++c) acc[c] = 0.f;

  for (int l = 0; l < 4; ++l) {
    int W = Wl[l], H = Hl[l], HW = W * H;
    float px = sx / sl[l] - 0.5f;
    float py = sy / sl[l] - 0.5f;
    float x0f = floorf(px), y0f = floorf(py);
    int x0 = (int)x0f, y0 = (int)y0f;
    float fx = px - x0f, fy = py - y0f;
    float wl_ = lw[l];
    float cw[4] = {(1.f - fx) * (1.f - fy) * wl_, fx * (1.f - fy) * wl_,
                   (1.f - fx) * fy * wl_, fx * fy * wl_};
    int cxi[4] = {x0, x0 + 1, x0, x0 + 1};
    int cyi[4] = {y0, y0, y0 + 1, y0 + 1};
    const float* base = fp[l] + ((size_t)(bb * D + g * CG + half * 32)) * HW;
    for (int k = 0; k < 4; ++k) {
      if (cxi[k] >= 0 && cxi[k] < W && cyi[k] >= 0 && cyi[k] < H) {
        float w = cw[k];
        const float* pp = base + cyi[k] * W + cxi[k];
        #pragma unroll
        for (int c = 0; c < 32; ++c) acc[c] += w * pp[(size_t)c * HW];
      }
    }
  }
  float* op = sampled + (((size_t)bn * G + g) * PIN + p) * CG + half * 32;
  #pragma unroll
  for (int c = 0; c < 32; ++c) op[c] = acc[c];
}

// ---------------- kernel 2: params GEMM (1200x256 @ 256x32768 -> bf16) ------
constexpr int BM2 = 32, BN2 = 128, BK2 = 32;
__global__ __launch_bounds__(256) void k_pgemm(
    const float* __restrict__ qf, const float* __restrict__ pgw,
    const float* __restrict__ pgb, unsigned short* __restrict__ params) {
  __shared__ float As[BK2][BM2 + 4];  // stride 36 floats (144B, 16B-aligned rows)
  __shared__ float Bs[BK2][BN2];
  int row0 = blockIdx.x * BM2;
  int col0 = blockIdx.y * BN2;
  int t = threadIdx.x;
  int tcol = t & 31, trow = t >> 5;
  float acc[4][4] = {};
  for (int k0 = 0; k0 < D; k0 += BK2) {
    {
      int m = t >> 3, kq = (t & 7) * 4;
      int grow = row0 + m;
      float4 v = make_float4(0.f, 0.f, 0.f, 0.f);
      if (grow < BN_TOT) v = *(const float4*)(qf + (size_t)grow * D + k0 + kq);
      As[kq + 0][m] = v.x; As[kq + 1][m] = v.y;
      As[kq + 2][m] = v.z; As[kq + 3][m] = v.w;
    }
    #pragma unroll
    for (int i = 0; i < 4; ++i) {
      int f4 = t + i * 256;
      int k = f4 >> 5, c4 = (f4 & 31) * 4;
      *(float4*)&Bs[k][c4] = *(const float4*)(pgw + (size_t)(k0 + k) * GT + col0 + c4);
    }
    __syncthreads();
    #pragma unroll
    for (int k = 0; k < BK2; ++k) {
      float4 av = *(const float4*)&As[k][trow * 4];
      float4 bv = *(const float4*)&Bs[k][tcol * 4];
      float a_[4] = {av.x, av.y, av.z, av.w};
      float b_[4] = {bv.x, bv.y, bv.z, bv.w};
      #pragma unroll
      for (int i = 0; i < 4; ++i)
        #pragma unroll
        for (int jj = 0; jj < 4; ++jj) acc[i][jj] += a_[i] * b_[jj];
    }
    __syncthreads();
  }
  #pragma unroll
  for (int i = 0; i < 4; ++i) {
    int grow = row0 + trow * 4 + i;
    if (grow < BN_TOT) {
      #pragma unroll
      for (int jj = 0; jj < 4; ++jj) {
        int gcol = col0 + tcol * 4 + jj;
        params[(size_t)grow * GT + gcol] = f2bf(acc[i][jj] + pgb[gcol]);
      }
    }
  }
}

// ---------------- kernel 3: per-(b,n,g) mixing -------------------------------
// h1 = sampled(32x64) @ M(64x64); relu(ln2); h2 = S(128x32) @ h1(32x64); relu(ln2)
__global__ __launch_bounds__(256) void k_mixing(
    const float* __restrict__ sampled, const unsigned short* __restrict__ params,
    unsigned short* __restrict__ h2out) {
  int blk = blockIdx.x;          // 0..4799
  int g = blk & 3;
  int bn = blk >> 2;
  const unsigned short* P = params + ((size_t)bn * GT) + (size_t)g * TOTAL;
  __shared__ float Sam[PIN * CG];   // 2048
  __shared__ float Ms[CG * CG];     // 4096
  __shared__ float H1[PIN * CG];    // 2048
  __shared__ float red[8];
  int t = threadIdx.x;
  const float* sp = sampled + (((size_t)bn * G + g) * PIN) * CG;
  for (int i = t; i < PIN * CG; i += 256) Sam[i] = sp[i];
  for (int i = t; i < CG * CG; i += 256) Ms[i] = bf2f(P[i]);
  __syncthreads();

  // h1: thread computes 8 elements: p = t>>3, d in [db, db+8)
  int p = t >> 3, db = (t & 7) * 8;
  float h[8] = {};
  for (int c = 0; c < CG; ++c) {
    float s = Sam[p * CG + c];
    #pragma unroll
    for (int i = 0; i < 8; ++i) h[i] += s * Ms[c * CG + db + i];
  }
  float a = 0.f, b2 = 0.f;
  #pragma unroll
  for (int i = 0; i < 8; ++i) { a += h[i]; b2 += h[i] * h[i]; }
  breduce2(a, b2, red);
  {
    float mu = a * (1.f / (PIN * CG));
    float var = b2 * (1.f / (PIN * CG)) - mu * mu;
    float rs = rsqrtf(var + 1e-5f);
    #pragma unroll
    for (int i = 0; i < 8; ++i) {
      float v = (h[i] - mu) * rs;
      H1[p * CG + db + i] = v > 0.f ? v : 0.f;
    }
  }
  __syncthreads();

  // h2: thread computes 32 elements: o = t>>1, d in [d2, d2+32)
  int o = t >> 1, d2 = (t & 1) * 32;
  float h2r[32] = {};
  for (int pp = 0; pp < PIN; ++pp) {
    float sv = bf2f(P[CG * CG + o * PIN + pp]);
    #pragma unroll
    for (int i = 0; i < 32; ++i) h2r[i] += sv * H1[pp * CG + d2 + i];
  }
  a = 0.f; b2 = 0.f;
  #pragma unroll
  for (int i = 0; i < 32; ++i) { a += h2r[i]; b2 += h2r[i] * h2r[i]; }
  breduce2(a, b2, red);
  {
    float mu = a * (1.f / (POUT * CG));
    float var = b2 * (1.f / (POUT * CG)) - mu * mu;
    float rs = rsqrtf(var + 1e-5f);
    unsigned short* dst = h2out + (size_t)bn * GT + (size_t)g * TOTAL + o * CG + d2;
    #pragma unroll
    for (int i = 0; i < 32; ++i) {
      float v = (h2r[i] - mu) * rs;
      dst[i] = f2bf(v > 0.f ? v : 0.f);
    }
  }
}

// ---------------- kernel 4: output GEMM partials -----------------------------
// parts[s] = h2[:, s*4096:(s+1)*4096] @ op_w[s*4096:(s+1)*4096, :]
constexpr int BM4 = 64, BN4 = 64, BK4 = 16, KSPLIT = 8, KCH = GT / KSPLIT;  // 4096
__global__ __launch_bounds__(256) void k_ogemm(
    const unsigned short* __restrict__ h2, const float* __restrict__ opw,
    float* __restrict__ parts) {
  __shared__ float As[BK4][BM4 + 4];  // stride 68 floats (272B, 16B-aligned rows)
  __shared__ float Bs[BK4][BN4];
  int row0 = blockIdx.x * BM4;
  int col0 = blockIdx.y * BN4;
  int s = blockIdx.z;
  int kbase = s * KCH;
  int t = threadIdx.x;
  int tcol = t & 15, trow = t >> 4;
  float acc[4][4] = {};
  for (int k0 = 0; k0 < KCH; k0 += BK4) {
    {
      int m = t >> 2, kq = (t & 3) * 4;
      int grow = row0 + m;
      unsigned short u0 = 0, u1 = 0, u2 = 0, u3 = 0;
      if (grow < BN_TOT) {
        const unsigned short* hp = h2 + (size_t)grow * GT + kbase + k0 + kq;
        uint2 v = *(const uint2*)hp;
        u0 = (unsigned short)(v.x & 0xffffu); u1 = (unsigned short)(v.x >> 16);
        u2 = (unsigned short)(v.y & 0xffffu); u3 = (unsigned short)(v.y >> 16);
      }
      As[kq + 0][m] = bf2f(u0); As[kq + 1][m] = bf2f(u1);
      As[kq + 2][m] = bf2f(u2); As[kq + 3][m] = bf2f(u3);
    }
    {
      int k = t >> 4, c4 = (t & 15) * 4;
      *(float4*)&Bs[k][c4] =
          *(const float4*)(opw + (size_t)(kbase + k0 + k) * D + col0 + c4);
    }
    __syncthreads();
    #pragma unroll
    for (int k = 0; k < BK4; ++k) {
      float4 av = *(const float4*)&As[k][trow * 4];
      float4 bv = *(const float4*)&Bs[k][tcol * 4];
      float a_[4] = {av.x, av.y, av.z, av.w};
      float b_[4] = {bv.x, bv.y, bv.z, bv.w};
      #pragma unroll
      for (int i = 0; i < 4; ++i)
        #pragma unroll
        for (int jj = 0; jj < 4; ++jj) acc[i][jj] += a_[i] * b_[jj];
    }
    __syncthreads();
  }
  #pragma unroll
  for (int i = 0; i < 4; ++i) {
    int grow = row0 + trow * 4 + i;
    if (grow < BN_TOT) {
      #pragma unroll
      for (int jj = 0; jj < 4; ++jj) {
        parts[((size_t)s * BN_TOT + grow) * D + col0 + tcol * 4 + jj] = acc[i][jj];
      }
    }
  }
}

// ---------------- kernel 5: K-split reduce + residual + LN1 ------------------
__global__ __launch_bounds__(256) void k_final(
    const float* __restrict__ qf, const float* __restrict__ opb,
    const float* __restrict__ parts, const float* __restrict__ lng,
    const float* __restrict__ lnb, float* __restrict__ out) {
  int bn = blockIdx.x;
  int d = threadIdx.x;
  float v = qf[(size_t)bn * D + d] + opb[d];
  #pragma unroll
  for (int s = 0; s < KSPLIT; ++s) v += parts[((size_t)s * BN_TOT + bn) * D + d];
  __shared__ float red[8];
  float a = v, b2 = v * v;
  breduce2(a, b2, red);
  float mu = a * (1.f / D);
  float var = b2 * (1.f / D) - mu * mu;
  float rs = rsqrtf(var + 1e-5f);
  out[(size_t)bn * D + d] = (v - mu) * rs * lng[d] + lnb[d];
}

}  // namespace

extern "C" void kernel_launch(void* const* d_in, const int* in_sizes, int n_in,
                              void* d_out, int out_size, void* d_ws, size_t ws_size,
                              hipStream_t stream) {
  const float* f0 = (const float*)d_in[0];
  const float* f1 = (const float*)d_in[1];
  const float* f2 = (const float*)d_in[2];
  const float* f3 = (const float*)d_in[3];
  const float* qf = (const float*)d_in[4];
  const float* roi = (const float*)d_in[5];
  const float* off_w = (const float*)d_in[6];
  const float* off_b = (const float*)d_in[7];
  const float* pg_w = (const float*)d_in[8];
  const float* pg_b = (const float*)d_in[9];
  const float* op_w = (const float*)d_in[10];
  const float* op_b = (const float*)d_in[11];
  const float* ln_g = (const float*)d_in[12];
  const float* ln_b = (const float*)d_in[13];
  float* out = (float*)d_out;

  // workspace layout (bytes):
  //   sampled  fp32 : 1200*4*32*64*4   =  39,321,600
  //   params   bf16 : 1200*32768*2     =  78,643,200
  //   h2       bf16 : 1200*32768*2     =  78,643,200
  //   parts    fp32 : 8*1200*256*4     =   9,830,400
  //   total ≈ 206.4 MB
  char* ws = (char*)d_ws;
  float* sampled = (float*)ws;
  unsigned short* params = (unsigned short*)(ws + 39321600ULL);
  unsigned short* h2 = (unsigned short*)(ws + 39321600ULL + 78643200ULL);
  float* parts = (float*)(ws + 39321600ULL + 78643200ULL + 78643200ULL);

  k_sample<<<BN_TOT, 256, 0, stream>>>(qf, roi, off_w, off_b, f0, f1, f2, f3, sampled);
  k_pgemm<<<dim3((BN_TOT + BM2 - 1) / BM2, GT / BN2), 256, 0, stream>>>(qf, pg_w, pg_b, params);
  k_mixing<<<BN_TOT * G, 256, 0, stream>>>(sampled, params, h2);
  k_ogemm<<<dim3((BN_TOT + BM4 - 1) / BM4, D / BN4, KSPLIT), 256, 0, stream>>>(h2, op_w, parts);
  k_final<<<BN_TOT, 256, 0, stream>>>(qf, op_b, parts, ln_g, ln_b, out);
}

// Round 2
// 681.878 us; speedup vs baseline: 1.7238x; 1.7238x over previous
//
#include <hip/hip_runtime.h>
#include <hip/hip_bf16.h>
#include <cstdint>

namespace {

constexpr int B = 4, N = 300, D = 256;
constexpr int G = 4, PIN = 32, POUT = 128;
constexpr int CG = D / G;                    // 64
constexpr int TOTAL = CG * CG + PIN * POUT;  // 8192
constexpr int BN_TOT = B * N;                // 1200
constexpr int BN_PAD = 1216;                 // 19 * 64
constexpr int GT = G * TOTAL;                // 32768

typedef short s16x8 __attribute__((ext_vector_type(8)));   // 8 bf16 = 4 VGPRs
typedef float f32x4 __attribute__((ext_vector_type(4)));

// ---- bf16 helpers (bit-level, RNE) ----
__device__ __forceinline__ float bf2f(unsigned short u) {
  union { unsigned int i; float f; } x; x.i = ((unsigned int)u) << 16; return x.f;
}
__device__ __forceinline__ unsigned short f2bf(float f) {
  union { float f; unsigned int i; } x; x.f = f;
  unsigned int r = x.i + 0x7fffu + ((x.i >> 16) & 1u);
  return (unsigned short)(r >> 16);
}

// block(256) reduction of two values (sum, sumsq)
__device__ __forceinline__ void breduce2(float& a, float& b, volatile float* red) {
  __syncthreads();
  #pragma unroll
  for (int off = 32; off; off >>= 1) {
    a += __shfl_down(a, off, 64);
    b += __shfl_down(b, off, 64);
  }
  int t = threadIdx.x;
  if ((t & 63) == 0) { red[t >> 6] = a; red[4 + (t >> 6)] = b; }
  __syncthreads();
  a = red[0] + red[1] + red[2] + red[3];
  b = red[4] + red[5] + red[6] + red[7];
}

// ---------------- prep: fp32 [R][C] -> bf16 transposed [C][R] ---------------
__global__ __launch_bounds__(256) void k_transpose(
    const float* __restrict__ in, unsigned short* __restrict__ out, int R, int C) {
  __shared__ unsigned short T[64][72];
  int c0 = blockIdx.x * 64;
  int r0 = blockIdx.y * 64;
  int t = threadIdx.x;
  #pragma unroll
  for (int i = 0; i < 4; ++i) {
    int u = t + i * 256;           // 1024 float4 units
    int rr = u >> 4, c4 = (u & 15) * 4;
    float4 v = *(const float4*)(in + (size_t)(r0 + rr) * C + c0 + c4);
    ushort4 w;
    w.x = f2bf(v.x); w.y = f2bf(v.y); w.z = f2bf(v.z); w.w = f2bf(v.w);
    *(ushort4*)&T[rr][c4] = w;
  }
  __syncthreads();
  #pragma unroll
  for (int i = 0; i < 2; ++i) {
    int u = t + i * 256;           // 512 16B-units of output
    int c = u >> 3, rr8 = (u & 7) * 8;
    unsigned short tmp[8];
    #pragma unroll
    for (int j = 0; j < 8; ++j) tmp[j] = T[rr8 + j][c];
    *(uint4*)(out + (size_t)(c0 + c) * R + r0 + rr8) = *(const uint4*)tmp;
  }
}

// ---------------- prep: qf fp32 [1200][256] -> bf16 [1216][256] -------------
__global__ __launch_bounds__(256) void k_cvt_qf(
    const float* __restrict__ qf, unsigned short* __restrict__ qb) {
  int e = (blockIdx.x * 256 + threadIdx.x) * 4;   // grid 304 -> 311296 elems
  int row = e >> 8;
  ushort4 w;
  if (row < BN_TOT) {
    float4 v = *(const float4*)(qf + e);
    w.x = f2bf(v.x); w.y = f2bf(v.y); w.z = f2bf(v.z); w.w = f2bf(v.w);
  } else {
    w.x = w.y = w.z = w.w = 0;
  }
  *(ushort4*)(qb + e) = w;
}

// ---------------- kernel 1: offset GEMM + bilinear sampling ----------------
__global__ __launch_bounds__(256) void k_sample(
    const float* __restrict__ qf, const float* __restrict__ roi,
    const float* __restrict__ off_w, const float* __restrict__ off_b,
    const float* __restrict__ f0, const float* __restrict__ f1,
    const float* __restrict__ f2, const float* __restrict__ f3,
    unsigned short* __restrict__ sampled) {
  int bn = blockIdx.x;
  int bb = bn / N;
  int t = threadIdx.x;
  __shared__ float q[D];
  __shared__ float off[G * PIN * 3];
  q[t] = qf[(size_t)bn * D + t];
  __syncthreads();
  for (int col = t; col < G * PIN * 3; col += 256) {
    float acc = off_b[col];
    #pragma unroll 4
    for (int d = 0; d < D; ++d) acc += q[d] * off_w[d * (G * PIN * 3) + col];
    off[col] = acc;
  }
  __syncthreads();

  float cx = roi[bn * 4 + 0], cy = roi[bn * 4 + 1];
  float z = roi[bn * 4 + 2], r = roi[bn * 4 + 3];
  float scale = exp2f(z);
  float rw = scale * exp2f(-0.5f * r);
  float rh = scale * exp2f(0.5f * r);

  int j = t >> 1;
  int half = t & 1;
  int g = j >> 5, p = j & 31;
  float sx = cx + off[j * 3 + 0] * rw;
  float sy = cy + off[j * 3 + 1] * rh;
  float sz = z + off[j * 3 + 2];

  float lw[4];
  {
    float m = -1e30f;
    #pragma unroll
    for (int l = 0; l < 4; ++l) {
      float dlt = sz - 3.0f - (float)l;
      lw[l] = -dlt * dlt * 0.5f;
      m = fmaxf(m, lw[l]);
    }
    float s = 0.f;
    #pragma unroll
    for (int l = 0; l < 4; ++l) { lw[l] = expf(lw[l] - m); s += lw[l]; }
    float inv = 1.f / s;
    #pragma unroll
    for (int l = 0; l < 4; ++l) lw[l] *= inv;
  }

  const float* fp[4] = {f0, f1, f2, f3};
  const int Wl[4] = {160, 80, 40, 20};
  const int Hl[4] = {100, 50, 25, 13};
  const float sl[4] = {8.f, 16.f, 32.f, 64.f};

  float acc[32];
  #pragma unroll
  for (int c = 0; c < 32; ++c) acc[c] = 0.f;

  for (int l = 0; l < 4; ++l) {
    int W = Wl[l], H = Hl[l], HW = W * H;
    float px = sx / sl[l] - 0.5f;
    float py = sy / sl[l] - 0.5f;
    float x0f = floorf(px), y0f = floorf(py);
    int x0 = (int)x0f, y0 = (int)y0f;
    float fx = px - x0f, fy = py - y0f;
    float wl_ = lw[l];
    float cw[4] = {(1.f - fx) * (1.f - fy) * wl_, fx * (1.f - fy) * wl_,
                   (1.f - fx) * fy * wl_, fx * fy * wl_};
    int cxi[4] = {x0, x0 + 1, x0, x0 + 1};
    int cyi[4] = {y0, y0, y0 + 1, y0 + 1};
    const float* base = fp[l] + ((size_t)(bb * D + g * CG + half * 32)) * HW;
    for (int k = 0; k < 4; ++k) {
      if (cxi[k] >= 0 && cxi[k] < W && cyi[k] >= 0 && cyi[k] < H) {
        float w = cw[k];
        const float* pp = base + cyi[k] * W + cxi[k];
        #pragma unroll
        for (int c = 0; c < 32; ++c) acc[c] += w * pp[(size_t)c * HW];
      }
    }
  }
  unsigned short* op = sampled + (((size_t)bn * G + g) * PIN + p) * CG + half * 32;
  #pragma unroll
  for (int c = 0; c < 32; ++c) op[c] = f2bf(acc[c]);
}

// ---------------- kernel 2: params GEMM via MFMA ----------------------------
// params[1200][32768] = qf_bf16[1200][256] @ pg_w[256][32768]  (+ bias, ->bf16)
// A = qf_bf16 [BN_PAD][256] (K-contig), B = pg_wT [32768][256] (K-contig)
__global__ __launch_bounds__(256) void k_pgemm(
    const unsigned short* __restrict__ A, const unsigned short* __restrict__ Bt,
    const float* __restrict__ pgb, unsigned short* __restrict__ params) {
  __shared__ unsigned short As[64][72];   // 9216 B
  __shared__ unsigned short Bs[128][72];  // 18432 B
  int col0 = blockIdx.x * 128;
  int row0 = blockIdx.y * 64;
  int t = threadIdx.x;
  int wave = t >> 6, lane = t & 63, lr = lane & 15, q = lane >> 4;
  f32x4 acc[4][2] = {};
  for (int k0 = 0; k0 < D; k0 += 64) {
    #pragma unroll
    for (int i = 0; i < 2; ++i) {             // A: 512 16B-units
      int u = t + i * 256;
      int r = u >> 3, kk = (u & 7) * 8;
      *(uint4*)&As[r][kk] = *(const uint4*)(A + (size_t)(row0 + r) * D + k0 + kk);
    }
    #pragma unroll
    for (int i = 0; i < 4; ++i) {             // B: 1024 16B-units
      int u = t + i * 256;
      int n = u >> 3, kk = (u & 7) * 8;
      *(uint4*)&Bs[n][kk] = *(const uint4*)(Bt + (size_t)(col0 + n) * D + k0 + kk);
    }
    __syncthreads();
    #pragma unroll
    for (int ks = 0; ks < 64; ks += 32) {
      s16x8 af[4], bf[2];
      #pragma unroll
      for (int mi = 0; mi < 4; ++mi)
        af[mi] = *(const s16x8*)&As[mi * 16 + lr][ks + q * 8];
      #pragma unroll
      for (int ni = 0; ni < 2; ++ni)
        bf[ni] = *(const s16x8*)&Bs[wave * 32 + ni * 16 + lr][ks + q * 8];
      #pragma unroll
      for (int mi = 0; mi < 4; ++mi)
        #pragma unroll
        for (int ni = 0; ni < 2; ++ni)
          acc[mi][ni] = __builtin_amdgcn_mfma_f32_16x16x32_bf16(af[mi], bf[ni], acc[mi][ni], 0, 0, 0);
    }
    __syncthreads();
  }
  #pragma unroll
  for (int ni = 0; ni < 2; ++ni) {
    int c = col0 + wave * 32 + ni * 16 + lr;
    float bias = pgb[c];
    #pragma unroll
    for (int mi = 0; mi < 4; ++mi) {
      #pragma unroll
      for (int rg = 0; rg < 4; ++rg) {
        int rr = row0 + mi * 16 + q * 4 + rg;
        if (rr < BN_TOT) params[(size_t)rr * GT + c] = f2bf(acc[mi][ni][rg] + bias);
      }
    }
  }
}

// ---------------- kernel 3: per-(b,n,g) mixing -------------------------------
__global__ __launch_bounds__(256) void k_mixing(
    const unsigned short* __restrict__ sampled, const unsigned short* __restrict__ params,
    unsigned short* __restrict__ h2out) {
  int blk = blockIdx.x;          // 0..4799
  int g = blk & 3;
  int bn = blk >> 2;
  const unsigned short* P = params + ((size_t)bn * GT) + (size_t)g * TOTAL;
  __shared__ float Sam[PIN * CG];   // 2048
  __shared__ float Ms[CG * CG];     // 4096
  __shared__ float H1[PIN * CG];    // 2048
  __shared__ float red[8];
  int t = threadIdx.x;
  const unsigned short* sp = sampled + (((size_t)bn * G + g) * PIN) * CG;
  for (int i = t; i < PIN * CG; i += 256) Sam[i] = bf2f(sp[i]);
  for (int i = t; i < CG * CG; i += 256) Ms[i] = bf2f(P[i]);
  __syncthreads();

  int p = t >> 3, db = (t & 7) * 8;
  float h[8] = {};
  for (int c = 0; c < CG; ++c) {
    float s = Sam[p * CG + c];
    #pragma unroll
    for (int i = 0; i < 8; ++i) h[i] += s * Ms[c * CG + db + i];
  }
  float a = 0.f, b2 = 0.f;
  #pragma unroll
  for (int i = 0; i < 8; ++i) { a += h[i]; b2 += h[i] * h[i]; }
  breduce2(a, b2, red);
  {
    float mu = a * (1.f / (PIN * CG));
    float var = b2 * (1.f / (PIN * CG)) - mu * mu;
    float rs = rsqrtf(var + 1e-5f);
    #pragma unroll
    for (int i = 0; i < 8; ++i) {
      float v = (h[i] - mu) * rs;
      H1[p * CG + db + i] = v > 0.f ? v : 0.f;
    }
  }
  __syncthreads();

  int o = t >> 1, d2 = (t & 1) * 32;
  float h2r[32] = {};
  for (int pp = 0; pp < PIN; ++pp) {
    float sv = bf2f(P[CG * CG + o * PIN + pp]);
    #pragma unroll
    for (int i = 0; i < 32; ++i) h2r[i] += sv * H1[pp * CG + d2 + i];
  }
  a = 0.f; b2 = 0.f;
  #pragma unroll
  for (int i = 0; i < 32; ++i) { a += h2r[i]; b2 += h2r[i] * h2r[i]; }
  breduce2(a, b2, red);
  {
    float mu = a * (1.f / (POUT * CG));
    float var = b2 * (1.f / (POUT * CG)) - mu * mu;
    float rs = rsqrtf(var + 1e-5f);
    unsigned short* dst = h2out + (size_t)bn * GT + (size_t)g * TOTAL + o * CG + d2;
    #pragma unroll
    for (int i = 0; i < 32; ++i) {
      float v = (h2r[i] - mu) * rs;
      dst[i] = f2bf(v > 0.f ? v : 0.f);
    }
  }
}

// ---------------- kernel 4: output GEMM via MFMA (K-split) ------------------
// parts[z][1216][256] = h2[:, z*1024:(z+1)*1024] @ op_w[z*1024:(z+1)*1024, :]
constexpr int KSPLIT = 32, KCH = GT / KSPLIT;  // 1024
__global__ __launch_bounds__(256) void k_ogemm(
    const unsigned short* __restrict__ A, const unsigned short* __restrict__ Bt,
    float* __restrict__ parts) {
  __shared__ unsigned short As[64][72];    //  9216 B
  __shared__ unsigned short Bs[256][72];   // 36864 B
  int row0 = blockIdx.x * 64;
  int z = blockIdx.y;
  int kbase = z * KCH;
  int t = threadIdx.x;
  int wave = t >> 6, lane = t & 63, lr = lane & 15, q = lane >> 4;
  f32x4 acc[4][4] = {};   // [mi][ni], wave covers cols wave*64 + ni*16
  for (int k0 = 0; k0 < KCH; k0 += 64) {
    #pragma unroll
    for (int i = 0; i < 2; ++i) {             // A: 512 16B-units
      int u = t + i * 256;
      int r = u >> 3, kk = (u & 7) * 8;
      *(uint4*)&As[r][kk] = *(const uint4*)(A + (size_t)(row0 + r) * GT + kbase + k0 + kk);
    }
    #pragma unroll
    for (int i = 0; i < 8; ++i) {             // B: 2048 16B-units
      int u = t + i * 256;
      int n = u >> 3, kk = (u & 7) * 8;
      *(uint4*)&Bs[n][kk] = *(const uint4*)(Bt + (size_t)n * GT + kbase + k0 + kk);
    }
    __syncthreads();
    #pragma unroll
    for (int ks = 0; ks < 64; ks += 32) {
      s16x8 af[4], bf[4];
      #pragma unroll
      for (int mi = 0; mi < 4; ++mi)
        af[mi] = *(const s16x8*)&As[mi * 16 + lr][ks + q * 8];
      #pragma unroll
      for (int ni = 0; ni < 4; ++ni)
        bf[ni] = *(const s16x8*)&Bs[wave * 64 + ni * 16 + lr][ks + q * 8];
      #pragma unroll
      for (int mi = 0; mi < 4; ++mi)
        #pragma unroll
        for (int ni = 0; ni < 4; ++ni)
          acc[mi][ni] = __builtin_amdgcn_mfma_f32_16x16x32_bf16(af[mi], bf[ni], acc[mi][ni], 0, 0, 0);
    }
    __syncthreads();
  }
  #pragma unroll
  for (int mi = 0; mi < 4; ++mi) {
    #pragma unroll
    for (int ni = 0; ni < 4; ++ni) {
      int c = wave * 64 + ni * 16 + lr;
      #pragma unroll
      for (int rg = 0; rg < 4; ++rg) {
        int rr = row0 + mi * 16 + q * 4 + rg;
        if (rr < BN_TOT)
          parts[((size_t)z * BN_PAD + rr) * D + c] = acc[mi][ni][rg];
      }
    }
  }
}

// ---------------- kernel 5: K-split reduce + residual + LN1 ------------------
__global__ __launch_bounds__(256) void k_final(
    const float* __restrict__ qf, const float* __restrict__ opb,
    const float* __restrict__ parts, const float* __restrict__ lng,
    const float* __restrict__ lnb, float* __restrict__ out) {
  int bn = blockIdx.x;
  int d = threadIdx.x;
  float v = qf[(size_t)bn * D + d] + opb[d];
  #pragma unroll
  for (int s = 0; s < KSPLIT; ++s) v += parts[((size_t)s * BN_PAD + bn) * D + d];
  __shared__ float red[8];
  float a = v, b2 = v * v;
  breduce2(a, b2, red);
  float mu = a * (1.f / D);
  float var = b2 * (1.f / D) - mu * mu;
  float rs = rsqrtf(var + 1e-5f);
  out[(size_t)bn * D + d] = (v - mu) * rs * lng[d] + lnb[d];
}

}  // namespace

extern "C" void kernel_launch(void* const* d_in, const int* in_sizes, int n_in,
                              void* d_out, int out_size, void* d_ws, size_t ws_size,
                              hipStream_t stream) {
  const float* f0 = (const float*)d_in[0];
  const float* f1 = (const float*)d_in[1];
  const float* f2 = (const float*)d_in[2];
  const float* f3 = (const float*)d_in[3];
  const float* qf = (const float*)d_in[4];
  const float* roi = (const float*)d_in[5];
  const float* off_w = (const float*)d_in[6];
  const float* off_b = (const float*)d_in[7];
  const float* pg_w = (const float*)d_in[8];
  const float* pg_b = (const float*)d_in[9];
  const float* op_w = (const float*)d_in[10];
  const float* op_b = (const float*)d_in[11];
  const float* ln_g = (const float*)d_in[12];
  const float* ln_b = (const float*)d_in[13];
  float* out = (float*)d_out;

  // workspace layout (bytes):
  //   sampled bf16 : 1200*4*32*64*2            = 19,660,800
  //   h2      bf16 : 1216*32768*2              = 79,691,776
  //   params  bf16 : 1216*32768*2              = 79,691,776
  //     (parts fp32 32*1216*256*4 = 39,845,888 aliases params after k_mixing)
  //   wT      bf16 : 32768*256*2               = 16,777,216  (pg_wT, then op_wT)
  //   qf_bf16      : 1216*256*2                =    622,592
  //   total ~ 196.4 MB
  char* ws = (char*)d_ws;
  unsigned short* sampled = (unsigned short*)ws;
  unsigned short* h2      = (unsigned short*)(ws + 19660800ULL);
  unsigned short* params  = (unsigned short*)(ws + 19660800ULL + 79691776ULL);
  float*          parts   = (float*)(ws + 19660800ULL + 79691776ULL);  // alias
  unsigned short* wT      = (unsigned short*)(ws + 19660800ULL + 2 * 79691776ULL);
  unsigned short* qfb     = (unsigned short*)(ws + 19660800ULL + 2 * 79691776ULL + 16777216ULL);

  // pg_wT = transpose(pg_w): in [256][32768] -> out [32768][256]
  k_transpose<<<dim3(GT / 64, D / 64), 256, 0, stream>>>(pg_w, wT, D, GT);
  k_cvt_qf<<<BN_PAD * D / 1024, 256, 0, stream>>>(qf, qfb);
  k_sample<<<BN_TOT, 256, 0, stream>>>(qf, roi, off_w, off_b, f0, f1, f2, f3, sampled);
  k_pgemm<<<dim3(GT / 128, BN_PAD / 64), 256, 0, stream>>>(qfb, wT, pg_b, params);
  k_mixing<<<BN_TOT * G, 256, 0, stream>>>(sampled, params, h2);
  // op_wT = transpose(op_w): in [32768][256] -> out [256][32768] (reuses wT slot)
  k_transpose<<<dim3(D / 64, GT / 64), 256, 0, stream>>>(op_w, wT, GT, D);
  k_ogemm<<<dim3(BN_PAD / 64, KSPLIT), 256, 0, stream>>>(h2, wT, parts);
  k_final<<<BN_TOT, 256, 0, stream>>>(qf, op_b, parts, ln_g, ln_b, out);
}

// Round 3
// 608.214 us; speedup vs baseline: 1.9326x; 1.1211x over previous
//
#include <hip/hip_runtime.h>
#include <hip/hip_bf16.h>
#include <cstdint>

namespace {

constexpr int B = 4, N = 300, D = 256;
constexpr int G = 4, PIN = 32, POUT = 128;
constexpr int CG = D / G;                    // 64
constexpr int TOTAL = CG * CG + PIN * POUT;  // 8192
constexpr int BN_TOT = B * N;                // 1200
constexpr int BN_PAD = 1216;                 // 19 * 64
constexpr int GT = G * TOTAL;                // 32768

typedef short s16x8 __attribute__((ext_vector_type(8)));   // 8 bf16 = 4 VGPRs
typedef float f32x4 __attribute__((ext_vector_type(4)));

// ---- bf16 helpers (bit-level, RNE) ----
__device__ __forceinline__ float bf2f(unsigned short u) {
  union { unsigned int i; float f; } x; x.i = ((unsigned int)u) << 16; return x.f;
}
__device__ __forceinline__ unsigned short f2bf(float f) {
  union { float f; unsigned int i; } x; x.f = f;
  unsigned int r = x.i + 0x7fffu + ((x.i >> 16) & 1u);
  return (unsigned short)(r >> 16);
}

__device__ __forceinline__ void breduce2(float& a, float& b, volatile float* red) {
  __syncthreads();
  #pragma unroll
  for (int off = 32; off; off >>= 1) {
    a += __shfl_down(a, off, 64);
    b += __shfl_down(b, off, 64);
  }
  int t = threadIdx.x;
  if ((t & 63) == 0) { red[t >> 6] = a; red[4 + (t >> 6)] = b; }
  __syncthreads();
  a = red[0] + red[1] + red[2] + red[3];
  b = red[4] + red[5] + red[6] + red[7];
}

// ---------------- prep: fp32 [R][C] -> bf16 transposed [C][R] ---------------
__global__ __launch_bounds__(256) void k_transpose(
    const float* __restrict__ in, unsigned short* __restrict__ out, int R, int C) {
  __shared__ unsigned short T[64][72];
  int c0 = blockIdx.x * 64;
  int r0 = blockIdx.y * 64;
  int t = threadIdx.x;
  #pragma unroll
  for (int i = 0; i < 4; ++i) {
    int u = t + i * 256;
    int rr = u >> 4, c4 = (u & 15) * 4;
    float4 v = *(const float4*)(in + (size_t)(r0 + rr) * C + c0 + c4);
    ushort4 w;
    w.x = f2bf(v.x); w.y = f2bf(v.y); w.z = f2bf(v.z); w.w = f2bf(v.w);
    *(ushort4*)&T[rr][c4] = w;
  }
  __syncthreads();
  #pragma unroll
  for (int i = 0; i < 2; ++i) {
    int u = t + i * 256;
    int c = u >> 3, rr8 = (u & 7) * 8;
    unsigned short tmp[8];
    #pragma unroll
    for (int j = 0; j < 8; ++j) tmp[j] = T[rr8 + j][c];
    *(uint4*)(out + (size_t)(c0 + c) * R + r0 + rr8) = *(const uint4*)tmp;
  }
}

// ------------- prep: feat fp32 [B][256][HW] -> bf16 [B][HW][256] ------------
__global__ __launch_bounds__(256) void k_featT(
    const float* __restrict__ in, unsigned short* __restrict__ out, int HW) {
  __shared__ unsigned short T[64][72];
  int hw0 = blockIdx.x * 64;
  int d0 = blockIdx.y * 64;
  int bb = blockIdx.z;
  int t = threadIdx.x;
  #pragma unroll
  for (int i = 0; i < 4; ++i) {
    int u = t + i * 256;
    int rr = u >> 4, c4 = (u & 15) * 4;   // rr = channel-in-tile, c4 = pixel
    if (hw0 + c4 + 3 < HW) {
      float4 v = *(const float4*)(in + ((size_t)(bb * D + d0 + rr)) * HW + hw0 + c4);
      ushort4 w;
      w.x = f2bf(v.x); w.y = f2bf(v.y); w.z = f2bf(v.z); w.w = f2bf(v.w);
      *(ushort4*)&T[rr][c4] = w;
    }
  }
  __syncthreads();
  #pragma unroll
  for (int i = 0; i < 2; ++i) {
    int u = t + i * 256;
    int p = u >> 3, dd8 = (u & 7) * 8;    // p = pixel-in-tile, dd8 = channel
    if (hw0 + p < HW) {
      unsigned short tmp[8];
      #pragma unroll
      for (int j = 0; j < 8; ++j) tmp[j] = T[dd8 + j][p];
      *(uint4*)(out + ((size_t)(bb * HW + hw0 + p)) * D + d0 + dd8) = *(const uint4*)tmp;
    }
  }
}

// ---------------- prep: qf fp32 [1200][256] -> bf16 [1216][256] -------------
__global__ __launch_bounds__(256) void k_cvt_qf(
    const float* __restrict__ qf, unsigned short* __restrict__ qb) {
  int e = (blockIdx.x * 256 + threadIdx.x) * 4;
  int row = e >> 8;
  ushort4 w;
  if (row < BN_TOT) {
    float4 v = *(const float4*)(qf + e);
    w.x = f2bf(v.x); w.y = f2bf(v.y); w.z = f2bf(v.z); w.w = f2bf(v.w);
  } else {
    w.x = w.y = w.z = w.w = 0;
  }
  *(ushort4*)(qb + e) = w;
}

// ---------------- kernel 0: offset GEMM (fp32) ------------------------------
// offsets[1200][384] = qf @ off_w + off_b ; block = 16 rows, 384 threads (col)
__global__ __launch_bounds__(384) void k_off(
    const float* __restrict__ qf, const float* __restrict__ offw,
    const float* __restrict__ offb, float* __restrict__ offsets) {
  int r0 = blockIdx.x * 16;
  int t = threadIdx.x;
  __shared__ float Q[16][256];
  for (int i = t; i < 16 * 256; i += 384)
    Q[i >> 8][i & 255] = qf[(size_t)(r0 + (i >> 8)) * 256 + (i & 255)];
  __syncthreads();
  float acc[16];
  float bias = offb[t];
  #pragma unroll
  for (int r = 0; r < 16; ++r) acc[r] = bias;
  for (int d = 0; d < 256; ++d) {
    float w = offw[(size_t)d * 384 + t];
    #pragma unroll
    for (int r = 0; r < 16; ++r) acc[r] += Q[r][d] * w;
  }
  #pragma unroll
  for (int r = 0; r < 16; ++r) offsets[(size_t)(r0 + r) * 384 + t] = acc[r];
}

// ---------------- kernel 1: bilinear gather from pixel-major bf16 -----------
// block = (bn); wave w = group g; lane = channel; 32 points per wave.
__global__ __launch_bounds__(256) void k_gather(
    const float* __restrict__ roi, const float* __restrict__ offsets,
    const unsigned short* __restrict__ featT, unsigned short* __restrict__ sampled) {
  int bn = blockIdx.x;
  int bb = bn / N;
  int t = threadIdx.x;
  __shared__ float spx[4][128], spy[4][128], swl[4][128];
  if (t < 128) {
    int j = t;
    float ox = offsets[(size_t)bn * 384 + j * 3 + 0];
    float oy = offsets[(size_t)bn * 384 + j * 3 + 1];
    float oz = offsets[(size_t)bn * 384 + j * 3 + 2];
    float cx = roi[bn * 4 + 0], cy = roi[bn * 4 + 1];
    float z = roi[bn * 4 + 2], r = roi[bn * 4 + 3];
    float scale = exp2f(z);
    float rw = scale * exp2f(-0.5f * r);
    float rh = scale * exp2f(0.5f * r);
    float sx = cx + ox * rw;
    float sy = cy + oy * rh;
    float sz = z + oz;
    float lw[4];
    float m = -1e30f;
    #pragma unroll
    for (int l = 0; l < 4; ++l) {
      float dlt = sz - 3.0f - (float)l;
      lw[l] = -dlt * dlt * 0.5f;
      m = fmaxf(m, lw[l]);
    }
    float s = 0.f;
    #pragma unroll
    for (int l = 0; l < 4; ++l) { lw[l] = expf(lw[l] - m); s += lw[l]; }
    float inv = 1.f / s;
    const float sl[4] = {8.f, 16.f, 32.f, 64.f};
    #pragma unroll
    for (int l = 0; l < 4; ++l) {
      spx[l][j] = sx / sl[l] - 0.5f;
      spy[l][j] = sy / sl[l] - 0.5f;
      swl[l][j] = lw[l] * inv;
    }
  }
  __syncthreads();
  int wave = t >> 6, lane = t & 63;
  const int Wl[4] = {160, 80, 40, 20};
  const int Hl[4] = {100, 50, 25, 13};
  const size_t loff[4] = {0, 16384000, 20480000, 21504000};
  for (int p = 0; p < 32; ++p) {
    int j = wave * 32 + p;
    float acc = 0.f;
    #pragma unroll
    for (int l = 0; l < 4; ++l) {
      int W = Wl[l], H = Hl[l];
      float px = spx[l][j], py = spy[l][j], wl_ = swl[l][j];
      float x0f = floorf(px), y0f = floorf(py);
      int x0 = (int)x0f, y0 = (int)y0f;
      float fx = px - x0f, fy = py - y0f;
      bool vx0 = (x0 >= 0) & (x0 < W);
      bool vx1 = (x0 + 1 >= 0) & (x0 + 1 < W);
      bool vy0 = (y0 >= 0) & (y0 < H);
      bool vy1 = (y0 + 1 >= 0) & (y0 + 1 < H);
      const unsigned short* base =
          featT + loff[l] + ((size_t)bb * H * W) * 256 + wave * 64 + lane;
      if (vy0) {
        float wy = (1.f - fy) * wl_;
        if (vx0) acc += (1.f - fx) * wy * bf2f(base[(size_t)(y0 * W + x0) * 256]);
        if (vx1) acc += fx * wy * bf2f(base[(size_t)(y0 * W + x0 + 1) * 256]);
      }
      if (vy1) {
        float wy = fy * wl_;
        if (vx0) acc += (1.f - fx) * wy * bf2f(base[(size_t)((y0 + 1) * W + x0) * 256]);
        if (vx1) acc += fx * wy * bf2f(base[(size_t)((y0 + 1) * W + x0 + 1) * 256]);
      }
    }
    sampled[(((size_t)bn * G + wave) * PIN + p) * CG + lane] = f2bf(acc);
  }
}

// ---------------- kernel 2: params GEMM via MFMA ----------------------------
__global__ __launch_bounds__(256) void k_pgemm(
    const unsigned short* __restrict__ A, const unsigned short* __restrict__ Bt,
    const float* __restrict__ pgb, unsigned short* __restrict__ params) {
  __shared__ unsigned short As[64][72];
  __shared__ unsigned short Bs[128][72];
  int col0 = blockIdx.x * 128;
  int row0 = blockIdx.y * 64;
  int t = threadIdx.x;
  int wave = t >> 6, lane = t & 63, lr = lane & 15, q = lane >> 4;
  f32x4 acc[4][2] = {};
  for (int k0 = 0; k0 < D; k0 += 64) {
    #pragma unroll
    for (int i = 0; i < 2; ++i) {
      int u = t + i * 256;
      int r = u >> 3, kk = (u & 7) * 8;
      *(uint4*)&As[r][kk] = *(const uint4*)(A + (size_t)(row0 + r) * D + k0 + kk);
    }
    #pragma unroll
    for (int i = 0; i < 4; ++i) {
      int u = t + i * 256;
      int n = u >> 3, kk = (u & 7) * 8;
      *(uint4*)&Bs[n][kk] = *(const uint4*)(Bt + (size_t)(col0 + n) * D + k0 + kk);
    }
    __syncthreads();
    #pragma unroll
    for (int ks = 0; ks < 64; ks += 32) {
      s16x8 af[4], bf[2];
      #pragma unroll
      for (int mi = 0; mi < 4; ++mi)
        af[mi] = *(const s16x8*)&As[mi * 16 + lr][ks + q * 8];
      #pragma unroll
      for (int ni = 0; ni < 2; ++ni)
        bf[ni] = *(const s16x8*)&Bs[wave * 32 + ni * 16 + lr][ks + q * 8];
      #pragma unroll
      for (int mi = 0; mi < 4; ++mi)
        #pragma unroll
        for (int ni = 0; ni < 2; ++ni)
          acc[mi][ni] = __builtin_amdgcn_mfma_f32_16x16x32_bf16(af[mi], bf[ni], acc[mi][ni], 0, 0, 0);
    }
    __syncthreads();
  }
  #pragma unroll
  for (int ni = 0; ni < 2; ++ni) {
    int c = col0 + wave * 32 + ni * 16 + lr;
    float bias = pgb[c];
    #pragma unroll
    for (int mi = 0; mi < 4; ++mi) {
      #pragma unroll
      for (int rg = 0; rg < 4; ++rg) {
        int rr = row0 + mi * 16 + q * 4 + rg;
        if (rr < BN_TOT) params[(size_t)rr * GT + c] = f2bf(acc[mi][ni][rg] + bias);
      }
    }
  }
}

// ---------------- kernel 3: per-(b,n,g) mixing -------------------------------
__global__ __launch_bounds__(256) void k_mixing(
    const unsigned short* __restrict__ sampled, const unsigned short* __restrict__ params,
    unsigned short* __restrict__ h2out) {
  int blk = blockIdx.x;
  int g = blk & 3;
  int bn = blk >> 2;
  const unsigned short* P = params + ((size_t)bn * GT) + (size_t)g * TOTAL;
  __shared__ float Sam[PIN * CG];
  __shared__ float Ms[CG * CG];
  __shared__ float H1[PIN * CG];
  __shared__ float red[8];
  int t = threadIdx.x;
  const unsigned short* sp = sampled + (((size_t)bn * G + g) * PIN) * CG;
  for (int i = t; i < PIN * CG; i += 256) Sam[i] = bf2f(sp[i]);
  for (int i = t; i < CG * CG; i += 256) Ms[i] = bf2f(P[i]);
  __syncthreads();

  int p = t >> 3, db = (t & 7) * 8;
  float h[8] = {};
  for (int c = 0; c < CG; ++c) {
    float s = Sam[p * CG + c];
    #pragma unroll
    for (int i = 0; i < 8; ++i) h[i] += s * Ms[c * CG + db + i];
  }
  float a = 0.f, b2 = 0.f;
  #pragma unroll
  for (int i = 0; i < 8; ++i) { a += h[i]; b2 += h[i] * h[i]; }
  breduce2(a, b2, red);
  {
    float mu = a * (1.f / (PIN * CG));
    float var = b2 * (1.f / (PIN * CG)) - mu * mu;
    float rs = rsqrtf(var + 1e-5f);
    #pragma unroll
    for (int i = 0; i < 8; ++i) {
      float v = (h[i] - mu) * rs;
      H1[p * CG + db + i] = v > 0.f ? v : 0.f;
    }
  }
  __syncthreads();

  int o = t >> 1, d2 = (t & 1) * 32;
  float h2r[32] = {};
  for (int pp = 0; pp < PIN; ++pp) {
    float sv = bf2f(P[CG * CG + o * PIN + pp]);
    #pragma unroll
    for (int i = 0; i < 32; ++i) h2r[i] += sv * H1[pp * CG + d2 + i];
  }
  a = 0.f; b2 = 0.f;
  #pragma unroll
  for (int i = 0; i < 32; ++i) { a += h2r[i]; b2 += h2r[i] * h2r[i]; }
  breduce2(a, b2, red);
  {
    float mu = a * (1.f / (POUT * CG));
    float var = b2 * (1.f / (POUT * CG)) - mu * mu;
    float rs = rsqrtf(var + 1e-5f);
    unsigned short* dst = h2out + (size_t)bn * GT + (size_t)g * TOTAL + o * CG + d2;
    #pragma unroll
    for (int i = 0; i < 32; ++i) {
      float v = (h2r[i] - mu) * rs;
      dst[i] = f2bf(v > 0.f ? v : 0.f);
    }
  }
}

// ---------------- kernel 4: output GEMM via MFMA (K-split) ------------------
constexpr int KSPLIT = 32, KCH = GT / KSPLIT;  // 1024
__global__ __launch_bounds__(256) void k_ogemm(
    const unsigned short* __restrict__ A, const unsigned short* __restrict__ Bt,
    float* __restrict__ parts) {
  __shared__ unsigned short As[64][72];
  __shared__ unsigned short Bs[256][72];
  int row0 = blockIdx.x * 64;
  int z = blockIdx.y;
  int kbase = z * KCH;
  int t = threadIdx.x;
  int wave = t >> 6, lane = t & 63, lr = lane & 15, q = lane >> 4;
  f32x4 acc[4][4] = {};
  for (int k0 = 0; k0 < KCH; k0 += 64) {
    #pragma unroll
    for (int i = 0; i < 2; ++i) {
      int u = t + i * 256;
      int r = u >> 3, kk = (u & 7) * 8;
      *(uint4*)&As[r][kk] = *(const uint4*)(A + (size_t)(row0 + r) * GT + kbase + k0 + kk);
    }
    #pragma unroll
    for (int i = 0; i < 8; ++i) {
      int u = t + i * 256;
      int n = u >> 3, kk = (u & 7) * 8;
      *(uint4*)&Bs[n][kk] = *(const uint4*)(Bt + (size_t)n * GT + kbase + k0 + kk);
    }
    __syncthreads();
    #pragma unroll
    for (int ks = 0; ks < 64; ks += 32) {
      s16x8 af[4], bf[4];
      #pragma unroll
      for (int mi = 0; mi < 4; ++mi)
        af[mi] = *(const s16x8*)&As[mi * 16 + lr][ks + q * 8];
      #pragma unroll
      for (int ni = 0; ni < 4; ++ni)
        bf[ni] = *(const s16x8*)&Bs[wave * 64 + ni * 16 + lr][ks + q * 8];
      #pragma unroll
      for (int mi = 0; mi < 4; ++mi)
        #pragma unroll
        for (int ni = 0; ni < 4; ++ni)
          acc[mi][ni] = __builtin_amdgcn_mfma_f32_16x16x32_bf16(af[mi], bf[ni], acc[mi][ni], 0, 0, 0);
    }
    __syncthreads();
  }
  #pragma unroll
  for (int mi = 0; mi < 4; ++mi) {
    #pragma unroll
    for (int ni = 0; ni < 4; ++ni) {
      int c = wave * 64 + ni * 16 + lr;
      #pragma unroll
      for (int rg = 0; rg < 4; ++rg) {
        int rr = row0 + mi * 16 + q * 4 + rg;
        if (rr < BN_TOT)
          parts[((size_t)z * BN_PAD + rr) * D + c] = acc[mi][ni][rg];
      }
    }
  }
}

// ---------------- kernel 5: K-split reduce + residual + LN1 ------------------
__global__ __launch_bounds__(256) void k_final(
    const float* __restrict__ qf, const float* __restrict__ opb,
    const float* __restrict__ parts, const float* __restrict__ lng,
    const float* __restrict__ lnb, float* __restrict__ out) {
  int bn = blockIdx.x;
  int d = threadIdx.x;
  float v = qf[(size_t)bn * D + d] + opb[d];
  #pragma unroll
  for (int s = 0; s < KSPLIT; ++s) v += parts[((size_t)s * BN_PAD + bn) * D + d];
  __shared__ float red[8];
  float a = v, b2 = v * v;
  breduce2(a, b2, red);
  float mu = a * (1.f / D);
  float var = b2 * (1.f / D) - mu * mu;
  float rs = rsqrtf(var + 1e-5f);
  out[(size_t)bn * D + d] = (v - mu) * rs * lng[d] + lnb[d];
}

}  // namespace

extern "C" void kernel_launch(void* const* d_in, const int* in_sizes, int n_in,
                              void* d_out, int out_size, void* d_ws, size_t ws_size,
                              hipStream_t stream) {
  const float* f0 = (const float*)d_in[0];
  const float* f1 = (const float*)d_in[1];
  const float* f2 = (const float*)d_in[2];
  const float* f3 = (const float*)d_in[3];
  const float* qf = (const float*)d_in[4];
  const float* roi = (const float*)d_in[5];
  const float* off_w = (const float*)d_in[6];
  const float* off_b = (const float*)d_in[7];
  const float* pg_w = (const float*)d_in[8];
  const float* pg_b = (const float*)d_in[9];
  const float* op_w = (const float*)d_in[10];
  const float* op_b = (const float*)d_in[11];
  const float* ln_g = (const float*)d_in[12];
  const float* ln_b = (const float*)d_in[13];
  float* out = (float*)d_out;

  // workspace layout (bytes):
  //   sampled bf16 : 19,660,800
  //   h2      bf16 : 79,691,776   (featT bf16 43,540,480 aliases this slot;
  //                                featT dead before k_mixing writes h2)
  //   params  bf16 : 79,691,776   (parts fp32 39,845,888 aliases after mixing)
  //   wT      bf16 : 16,777,216   (pg_wT, then op_wT)
  //   qf_bf16      :    622,592
  //   offsets fp32 :  1,843,200
  //   total ~ 198.3 MB
  char* ws = (char*)d_ws;
  unsigned short* sampled = (unsigned short*)ws;
  unsigned short* h2      = (unsigned short*)(ws + 19660800ULL);
  unsigned short* featT   = h2;  // alias
  unsigned short* params  = (unsigned short*)(ws + 19660800ULL + 79691776ULL);
  float*          parts   = (float*)(ws + 19660800ULL + 79691776ULL);  // alias
  unsigned short* wT      = (unsigned short*)(ws + 19660800ULL + 2 * 79691776ULL);
  unsigned short* qfb     = (unsigned short*)(ws + 19660800ULL + 2 * 79691776ULL + 16777216ULL);
  float*          offsets = (float*)(ws + 19660800ULL + 2 * 79691776ULL + 16777216ULL + 622592ULL);

  // feat transposes: featT[b][hw][256] bf16, per level
  k_featT<<<dim3(250, 4, B), 256, 0, stream>>>(f0, featT + 0,        16000);
  k_featT<<<dim3( 63, 4, B), 256, 0, stream>>>(f1, featT + 16384000, 4000);
  k_featT<<<dim3( 16, 4, B), 256, 0, stream>>>(f2, featT + 20480000, 1000);
  k_featT<<<dim3(  5, 4, B), 256, 0, stream>>>(f3, featT + 21504000, 260);
  k_off<<<BN_TOT / 16, 384, 0, stream>>>(qf, off_w, off_b, offsets);
  k_transpose<<<dim3(GT / 64, D / 64), 256, 0, stream>>>(pg_w, wT, D, GT);
  k_cvt_qf<<<BN_PAD * D / 1024, 256, 0, stream>>>(qf, qfb);
  k_gather<<<BN_TOT, 256, 0, stream>>>(roi, offsets, featT, sampled);
  k_pgemm<<<dim3(GT / 128, BN_PAD / 64), 256, 0, stream>>>(qfb, wT, pg_b, params);
  k_mixing<<<BN_TOT * G, 256, 0, stream>>>(sampled, params, h2);
  k_transpose<<<dim3(D / 64, GT / 64), 256, 0, stream>>>(op_w, wT, GT, D);
  k_ogemm<<<dim3(BN_PAD / 64, KSPLIT), 256, 0, stream>>>(h2, wT, parts);
  k_final<<<BN_TOT, 256, 0, stream>>>(qf, op_b, parts, ln_g, ln_b, out);
}

// Round 4
// 482.218 us; speedup vs baseline: 2.4376x; 1.2613x over previous
//
#include <hip/hip_runtime.h>
#include <hip/hip_bf16.h>
#include <cstdint>

namespace {

constexpr int B = 4, N = 300, D = 256;
constexpr int G = 4, PIN = 32, POUT = 128;
constexpr int CG = D / G;                    // 64
constexpr int TOTAL = CG * CG + PIN * POUT;  // 8192
constexpr int BN_TOT = B * N;                // 1200
constexpr int BN_PAD = 1216;                 // 19 * 64
constexpr int GT = G * TOTAL;                // 32768

typedef short s16x8 __attribute__((ext_vector_type(8)));   // 8 bf16 = 4 VGPRs
typedef float f32x4 __attribute__((ext_vector_type(4)));

// ---- bf16 helpers (bit-level, RNE) ----
__device__ __forceinline__ float bf2f(unsigned short u) {
  union { unsigned int i; float f; } x; x.i = ((unsigned int)u) << 16; return x.f;
}
__device__ __forceinline__ unsigned short f2bf(float f) {
  union { float f; unsigned int i; } x; x.f = f;
  unsigned int r = x.i + 0x7fffu + ((x.i >> 16) & 1u);
  return (unsigned short)(r >> 16);
}

__device__ __forceinline__ void breduce2(float& a, float& b, volatile float* red) {
  __syncthreads();
  #pragma unroll
  for (int off = 32; off; off >>= 1) {
    a += __shfl_down(a, off, 64);
    b += __shfl_down(b, off, 64);
  }
  int t = threadIdx.x;
  if ((t & 63) == 0) { red[t >> 6] = a; red[4 + (t >> 6)] = b; }
  __syncthreads();
  a = red[0] + red[1] + red[2] + red[3];
  b = red[4] + red[5] + red[6] + red[7];
}

// ---------------- prep: fp32 [R][C] -> bf16 transposed [C][R] ---------------
__global__ __launch_bounds__(256) void k_transpose(
    const float* __restrict__ in, unsigned short* __restrict__ out, int R, int C) {
  __shared__ unsigned short T[64][72];
  int c0 = blockIdx.x * 64;
  int r0 = blockIdx.y * 64;
  int t = threadIdx.x;
  #pragma unroll
  for (int i = 0; i < 4; ++i) {
    int u = t + i * 256;
    int rr = u >> 4, c4 = (u & 15) * 4;
    float4 v = *(const float4*)(in + (size_t)(r0 + rr) * C + c0 + c4);
    ushort4 w;
    w.x = f2bf(v.x); w.y = f2bf(v.y); w.z = f2bf(v.z); w.w = f2bf(v.w);
    *(ushort4*)&T[rr][c4] = w;
  }
  __syncthreads();
  #pragma unroll
  for (int i = 0; i < 2; ++i) {
    int u = t + i * 256;
    int c = u >> 3, rr8 = (u & 7) * 8;
    unsigned short tmp[8];
    #pragma unroll
    for (int j = 0; j < 8; ++j) tmp[j] = T[rr8 + j][c];
    *(uint4*)(out + (size_t)(c0 + c) * R + r0 + rr8) = *(const uint4*)tmp;
  }
}

// ------------- prep: feat fp32 [B][256][HW] -> bf16 [B][HW][256] ------------
__global__ __launch_bounds__(256) void k_featT(
    const float* __restrict__ in, unsigned short* __restrict__ out, int HW) {
  __shared__ unsigned short T[64][72];
  int hw0 = blockIdx.x * 64;
  int d0 = blockIdx.y * 64;
  int bb = blockIdx.z;
  int t = threadIdx.x;
  #pragma unroll
  for (int i = 0; i < 4; ++i) {
    int u = t + i * 256;
    int rr = u >> 4, c4 = (u & 15) * 4;   // rr = channel-in-tile, c4 = pixel
    if (hw0 + c4 + 3 < HW) {
      float4 v = *(const float4*)(in + ((size_t)(bb * D + d0 + rr)) * HW + hw0 + c4);
      ushort4 w;
      w.x = f2bf(v.x); w.y = f2bf(v.y); w.z = f2bf(v.z); w.w = f2bf(v.w);
      *(ushort4*)&T[rr][c4] = w;
    }
  }
  __syncthreads();
  #pragma unroll
  for (int i = 0; i < 2; ++i) {
    int u = t + i * 256;
    int p = u >> 3, dd8 = (u & 7) * 8;    // p = pixel-in-tile, dd8 = channel
    if (hw0 + p < HW) {
      unsigned short tmp[8];
      #pragma unroll
      for (int j = 0; j < 8; ++j) tmp[j] = T[dd8 + j][p];
      *(uint4*)(out + ((size_t)(bb * HW + hw0 + p)) * D + d0 + dd8) = *(const uint4*)tmp;
    }
  }
}

// ---------------- prep: qf fp32 [1200][256] -> bf16 [1216][256] -------------
__global__ __launch_bounds__(256) void k_cvt_qf(
    const float* __restrict__ qf, unsigned short* __restrict__ qb) {
  int e = (blockIdx.x * 256 + threadIdx.x) * 4;
  int row = e >> 8;
  ushort4 w;
  if (row < BN_TOT) {
    float4 v = *(const float4*)(qf + e);
    w.x = f2bf(v.x); w.y = f2bf(v.y); w.z = f2bf(v.z); w.w = f2bf(v.w);
  } else {
    w.x = w.y = w.z = w.w = 0;
  }
  *(ushort4*)(qb + e) = w;
}

// ---------------- kernel 0: offset GEMM (fp32) ------------------------------
__global__ __launch_bounds__(384) void k_off(
    const float* __restrict__ qf, const float* __restrict__ offw,
    const float* __restrict__ offb, float* __restrict__ offsets) {
  int r0 = blockIdx.x * 16;
  int t = threadIdx.x;
  __shared__ float Q[16][256];
  for (int i = t; i < 16 * 256; i += 384)
    Q[i >> 8][i & 255] = qf[(size_t)(r0 + (i >> 8)) * 256 + (i & 255)];
  __syncthreads();
  float acc[16];
  float bias = offb[t];
  #pragma unroll
  for (int r = 0; r < 16; ++r) acc[r] = bias;
  for (int d = 0; d < 256; ++d) {
    float w = offw[(size_t)d * 384 + t];
    #pragma unroll
    for (int r = 0; r < 16; ++r) acc[r] += Q[r][d] * w;
  }
  #pragma unroll
  for (int r = 0; r < 16; ++r) offsets[(size_t)(r0 + r) * 384 + t] = acc[r];
}

// ---------------- kernel 1: bilinear gather, branch-free + deep MLP ---------
// Stage 1: LDS table of 2048 (offset, weight) pairs for 128 pts x 4 lvl x 4 cor.
// Stage 2: wave = group; half-wave = point; lane covers 2 channels via uint.
__global__ __launch_bounds__(256) void k_gather(
    const float* __restrict__ roi, const float* __restrict__ offsets,
    const unsigned short* __restrict__ featT, unsigned short* __restrict__ sampled) {
  int bn = blockIdx.x;
  int bb = bn / N;
  int t = threadIdx.x;
  __shared__ int   widx[2048];   // [j][l][corner] element offset into featT
  __shared__ float wval[2048];

  const int Wl[4] = {160, 80, 40, 20};
  const int Hl[4] = {100, 50, 25, 13};
  const int loff[4] = {0, 16384000, 20480000, 21504000};
  const int HWl[4] = {16000, 4000, 1000, 260};
  const float sl[4] = {8.f, 16.f, 32.f, 64.f};

  float cx = roi[bn * 4 + 0], cy = roi[bn * 4 + 1];
  float z = roi[bn * 4 + 2], r = roi[bn * 4 + 3];
  float scale = exp2f(z);
  float rwx = scale * exp2f(-0.5f * r);
  float rhy = scale * exp2f(0.5f * r);

  #pragma unroll
  for (int task = t; task < 512; task += 256) {   // task = j*4 + l
    int j = task >> 2, l = task & 3;
    float ox = offsets[(size_t)bn * 384 + j * 3 + 0];
    float oy = offsets[(size_t)bn * 384 + j * 3 + 1];
    float oz = offsets[(size_t)bn * 384 + j * 3 + 2];
    float sx = cx + ox * rwx;
    float sy = cy + oy * rhy;
    float sz = z + oz;
    float lw[4];
    float m = -1e30f;
    #pragma unroll
    for (int ll = 0; ll < 4; ++ll) {
      float dlt = sz - 3.0f - (float)ll;
      lw[ll] = -dlt * dlt * 0.5f;
      m = fmaxf(m, lw[ll]);
    }
    float s = 0.f;
    #pragma unroll
    for (int ll = 0; ll < 4; ++ll) { lw[ll] = expf(lw[ll] - m); s += lw[ll]; }
    float wl_ = lw[l] / s;

    int W = Wl[l], H = Hl[l];
    float px = sx / sl[l] - 0.5f;
    float py = sy / sl[l] - 0.5f;
    float x0f = floorf(px), y0f = floorf(py);
    int x0 = (int)x0f, y0 = (int)y0f;
    float fx = px - x0f, fy = py - y0f;
    int base = loff[l] + bb * HWl[l] * 256;
    #pragma unroll
    for (int k = 0; k < 4; ++k) {
      int xi = x0 + (k & 1), yi = y0 + (k >> 1);
      bool valid = (xi >= 0) & (xi < W) & (yi >= 0) & (yi < H);
      int xc = min(max(xi, 0), W - 1), yc = min(max(yi, 0), H - 1);
      float wgt = ((k & 1) ? fx : 1.f - fx) * ((k >> 1) ? fy : 1.f - fy) * wl_;
      widx[j * 16 + l * 4 + k] = base + (yc * W + xc) * 256;
      wval[j * 16 + l * 4 + k] = valid ? wgt : 0.f;
    }
  }
  __syncthreads();

  int wave = t >> 6, lane = t & 63;
  int half = lane >> 5, ln = lane & 31;
  const unsigned short* fb = featT + wave * 64 + ln * 2;
  #pragma unroll 2
  for (int it = 0; it < 16; ++it) {
    int p = it * 2 + half;
    int j = wave * 32 + p;
    int ix[16]; float w[16]; unsigned int u[16];
    #pragma unroll
    for (int k = 0; k < 16; ++k) { ix[k] = widx[j * 16 + k]; w[k] = wval[j * 16 + k]; }
    #pragma unroll
    for (int k = 0; k < 16; ++k) u[k] = *(const unsigned int*)(fb + ix[k]);
    float a0 = 0.f, a1 = 0.f;
    #pragma unroll
    for (int k = 0; k < 16; ++k) {
      a0 += w[k] * bf2f((unsigned short)(u[k] & 0xffffu));
      a1 += w[k] * bf2f((unsigned short)(u[k] >> 16));
    }
    unsigned int packed = (unsigned int)f2bf(a0) | ((unsigned int)f2bf(a1) << 16);
    *(unsigned int*)(sampled + (((size_t)bn * G + wave) * PIN + p) * CG + ln * 2) = packed;
  }
}

// ---------------- kernel 2: params GEMM via MFMA ----------------------------
__global__ __launch_bounds__(256) void k_pgemm(
    const unsigned short* __restrict__ A, const unsigned short* __restrict__ Bt,
    const float* __restrict__ pgb, unsigned short* __restrict__ params) {
  __shared__ unsigned short As[64][72];
  __shared__ unsigned short Bs[128][72];
  int col0 = blockIdx.x * 128;
  int row0 = blockIdx.y * 64;
  int t = threadIdx.x;
  int wave = t >> 6, lane = t & 63, lr = lane & 15, q = lane >> 4;
  f32x4 acc[4][2] = {};
  for (int k0 = 0; k0 < D; k0 += 64) {
    #pragma unroll
    for (int i = 0; i < 2; ++i) {
      int u = t + i * 256;
      int r = u >> 3, kk = (u & 7) * 8;
      *(uint4*)&As[r][kk] = *(const uint4*)(A + (size_t)(row0 + r) * D + k0 + kk);
    }
    #pragma unroll
    for (int i = 0; i < 4; ++i) {
      int u = t + i * 256;
      int n = u >> 3, kk = (u & 7) * 8;
      *(uint4*)&Bs[n][kk] = *(const uint4*)(Bt + (size_t)(col0 + n) * D + k0 + kk);
    }
    __syncthreads();
    #pragma unroll
    for (int ks = 0; ks < 64; ks += 32) {
      s16x8 af[4], bf[2];
      #pragma unroll
      for (int mi = 0; mi < 4; ++mi)
        af[mi] = *(const s16x8*)&As[mi * 16 + lr][ks + q * 8];
      #pragma unroll
      for (int ni = 0; ni < 2; ++ni)
        bf[ni] = *(const s16x8*)&Bs[wave * 32 + ni * 16 + lr][ks + q * 8];
      #pragma unroll
      for (int mi = 0; mi < 4; ++mi)
        #pragma unroll
        for (int ni = 0; ni < 2; ++ni)
          acc[mi][ni] = __builtin_amdgcn_mfma_f32_16x16x32_bf16(af[mi], bf[ni], acc[mi][ni], 0, 0, 0);
    }
    __syncthreads();
  }
  #pragma unroll
  for (int ni = 0; ni < 2; ++ni) {
    int c = col0 + wave * 32 + ni * 16 + lr;
    float bias = pgb[c];
    #pragma unroll
    for (int mi = 0; mi < 4; ++mi) {
      #pragma unroll
      for (int rg = 0; rg < 4; ++rg) {
        int rr = row0 + mi * 16 + q * 4 + rg;
        if (rr < BN_TOT) params[(size_t)rr * GT + c] = f2bf(acc[mi][ni][rg] + bias);
      }
    }
  }
}

// ---------------- kernel 3: per-(b,n,g) mixing -------------------------------
__global__ __launch_bounds__(256) void k_mixing(
    const unsigned short* __restrict__ sampled, const unsigned short* __restrict__ params,
    unsigned short* __restrict__ h2out) {
  int blk = blockIdx.x;
  int g = blk & 3;
  int bn = blk >> 2;
  const unsigned short* P = params + ((size_t)bn * GT) + (size_t)g * TOTAL;
  __shared__ float Sam[PIN * CG];
  __shared__ float Ms[CG * CG];
  __shared__ float H1[PIN * CG];
  __shared__ float red[8];
  int t = threadIdx.x;
  const unsigned short* sp = sampled + (((size_t)bn * G + g) * PIN) * CG;
  for (int i = t; i < PIN * CG; i += 256) Sam[i] = bf2f(sp[i]);
  for (int i = t; i < CG * CG; i += 256) Ms[i] = bf2f(P[i]);
  __syncthreads();

  int p = t >> 3, db = (t & 7) * 8;
  float h[8] = {};
  for (int c = 0; c < CG; ++c) {
    float s = Sam[p * CG + c];
    #pragma unroll
    for (int i = 0; i < 8; ++i) h[i] += s * Ms[c * CG + db + i];
  }
  float a = 0.f, b2 = 0.f;
  #pragma unroll
  for (int i = 0; i < 8; ++i) { a += h[i]; b2 += h[i] * h[i]; }
  breduce2(a, b2, red);
  {
    float mu = a * (1.f / (PIN * CG));
    float var = b2 * (1.f / (PIN * CG)) - mu * mu;
    float rs = rsqrtf(var + 1e-5f);
    #pragma unroll
    for (int i = 0; i < 8; ++i) {
      float v = (h[i] - mu) * rs;
      H1[p * CG + db + i] = v > 0.f ? v : 0.f;
    }
  }
  __syncthreads();

  int o = t >> 1, d2 = (t & 1) * 32;
  float h2r[32] = {};
  for (int pp = 0; pp < PIN; ++pp) {
    float sv = bf2f(P[CG * CG + o * PIN + pp]);
    #pragma unroll
    for (int i = 0; i < 32; ++i) h2r[i] += sv * H1[pp * CG + d2 + i];
  }
  a = 0.f; b2 = 0.f;
  #pragma unroll
  for (int i = 0; i < 32; ++i) { a += h2r[i]; b2 += h2r[i] * h2r[i]; }
  breduce2(a, b2, red);
  {
    float mu = a * (1.f / (POUT * CG));
    float var = b2 * (1.f / (POUT * CG)) - mu * mu;
    float rs = rsqrtf(var + 1e-5f);
    unsigned short* dst = h2out + (size_t)bn * GT + (size_t)g * TOTAL + o * CG + d2;
    #pragma unroll
    for (int i = 0; i < 32; ++i) {
      float v = (h2r[i] - mu) * rs;
      dst[i] = f2bf(v > 0.f ? v : 0.f);
    }
  }
}

// ---------------- kernel 4: output GEMM via MFMA (K-split) ------------------
constexpr int KSPLIT = 32, KCH = GT / KSPLIT;  // 1024
__global__ __launch_bounds__(256) void k_ogemm(
    const unsigned short* __restrict__ A, const unsigned short* __restrict__ Bt,
    float* __restrict__ parts) {
  __shared__ unsigned short As[64][72];
  __shared__ unsigned short Bs[256][72];
  int row0 = blockIdx.x * 64;
  int z = blockIdx.y;
  int kbase = z * KCH;
  int t = threadIdx.x;
  int wave = t >> 6, lane = t & 63, lr = lane & 15, q = lane >> 4;
  f32x4 acc[4][4] = {};
  for (int k0 = 0; k0 < KCH; k0 += 64) {
    #pragma unroll
    for (int i = 0; i < 2; ++i) {
      int u = t + i * 256;
      int r = u >> 3, kk = (u & 7) * 8;
      *(uint4*)&As[r][kk] = *(const uint4*)(A + (size_t)(row0 + r) * GT + kbase + k0 + kk);
    }
    #pragma unroll
    for (int i = 0; i < 8; ++i) {
      int u = t + i * 256;
      int n = u >> 3, kk = (u & 7) * 8;
      *(uint4*)&Bs[n][kk] = *(const uint4*)(Bt + (size_t)n * GT + kbase + k0 + kk);
    }
    __syncthreads();
    #pragma unroll
    for (int ks = 0; ks < 64; ks += 32) {
      s16x8 af[4], bf[4];
      #pragma unroll
      for (int mi = 0; mi < 4; ++mi)
        af[mi] = *(const s16x8*)&As[mi * 16 + lr][ks + q * 8];
      #pragma unroll
      for (int ni = 0; ni < 4; ++ni)
        bf[ni] = *(const s16x8*)&Bs[wave * 64 + ni * 16 + lr][ks + q * 8];
      #pragma unroll
      for (int mi = 0; mi < 4; ++mi)
        #pragma unroll
        for (int ni = 0; ni < 4; ++ni)
          acc[mi][ni] = __builtin_amdgcn_mfma_f32_16x16x32_bf16(af[mi], bf[ni], acc[mi][ni], 0, 0, 0);
    }
    __syncthreads();
  }
  #pragma unroll
  for (int mi = 0; mi < 4; ++mi) {
    #pragma unroll
    for (int ni = 0; ni < 4; ++ni) {
      int c = wave * 64 + ni * 16 + lr;
      #pragma unroll
      for (int rg = 0; rg < 4; ++rg) {
        int rr = row0 + mi * 16 + q * 4 + rg;
        if (rr < BN_TOT)
          parts[((size_t)z * BN_PAD + rr) * D + c] = acc[mi][ni][rg];
      }
    }
  }
}

// ---------------- kernel 5: K-split reduce + residual + LN1 ------------------
__global__ __launch_bounds__(256) void k_final(
    const float* __restrict__ qf, const float* __restrict__ opb,
    const float* __restrict__ parts, const float* __restrict__ lng,
    const float* __restrict__ lnb, float* __restrict__ out) {
  int bn = blockIdx.x;
  int d = threadIdx.x;
  float v = qf[(size_t)bn * D + d] + opb[d];
  #pragma unroll
  for (int s = 0; s < KSPLIT; ++s) v += parts[((size_t)s * BN_PAD + bn) * D + d];
  __shared__ float red[8];
  float a = v, b2 = v * v;
  breduce2(a, b2, red);
  float mu = a * (1.f / D);
  float var = b2 * (1.f / D) - mu * mu;
  float rs = rsqrtf(var + 1e-5f);
  out[(size_t)bn * D + d] = (v - mu) * rs * lng[d] + lnb[d];
}

}  // namespace

extern "C" void kernel_launch(void* const* d_in, const int* in_sizes, int n_in,
                              void* d_out, int out_size, void* d_ws, size_t ws_size,
                              hipStream_t stream) {
  const float* f0 = (const float*)d_in[0];
  const float* f1 = (const float*)d_in[1];
  const float* f2 = (const float*)d_in[2];
  const float* f3 = (const float*)d_in[3];
  const float* qf = (const float*)d_in[4];
  const float* roi = (const float*)d_in[5];
  const float* off_w = (const float*)d_in[6];
  const float* off_b = (const float*)d_in[7];
  const float* pg_w = (const float*)d_in[8];
  const float* pg_b = (const float*)d_in[9];
  const float* op_w = (const float*)d_in[10];
  const float* op_b = (const float*)d_in[11];
  const float* ln_g = (const float*)d_in[12];
  const float* ln_b = (const float*)d_in[13];
  float* out = (float*)d_out;

  // workspace layout (bytes):
  //   sampled bf16 : 19,660,800
  //   h2      bf16 : 79,691,776   (featT bf16 43,540,480 aliases this slot)
  //   params  bf16 : 79,691,776   (parts fp32 39,845,888 aliases after mixing)
  //   wT      bf16 : 16,777,216   (pg_wT, then op_wT)
  //   qf_bf16      :    622,592
  //   offsets fp32 :  1,843,200
  //   total ~ 198.3 MB
  char* ws = (char*)d_ws;
  unsigned short* sampled = (unsigned short*)ws;
  unsigned short* h2      = (unsigned short*)(ws + 19660800ULL);
  unsigned short* featT   = h2;  // alias
  unsigned short* params  = (unsigned short*)(ws + 19660800ULL + 79691776ULL);
  float*          parts   = (float*)(ws + 19660800ULL + 79691776ULL);  // alias
  unsigned short* wT      = (unsigned short*)(ws + 19660800ULL + 2 * 79691776ULL);
  unsigned short* qfb     = (unsigned short*)(ws + 19660800ULL + 2 * 79691776ULL + 16777216ULL);
  float*          offsets = (float*)(ws + 19660800ULL + 2 * 79691776ULL + 16777216ULL + 622592ULL);

  k_featT<<<dim3(250, 4, B), 256, 0, stream>>>(f0, featT + 0,        16000);
  k_featT<<<dim3( 63, 4, B), 256, 0, stream>>>(f1, featT + 16384000, 4000);
  k_featT<<<dim3( 16, 4, B), 256, 0, stream>>>(f2, featT + 20480000, 1000);
  k_featT<<<dim3(  5, 4, B), 256, 0, stream>>>(f3, featT + 21504000, 260);
  k_off<<<BN_TOT / 16, 384, 0, stream>>>(qf, off_w, off_b, offsets);
  k_transpose<<<dim3(GT / 64, D / 64), 256, 0, stream>>>(pg_w, wT, D, GT);
  k_cvt_qf<<<BN_PAD * D / 1024, 256, 0, stream>>>(qf, qfb);
  k_gather<<<BN_TOT, 256, 0, stream>>>(roi, offsets, featT, sampled);
  k_pgemm<<<dim3(GT / 128, BN_PAD / 64), 256, 0, stream>>>(qfb, wT, pg_b, params);
  k_mixing<<<BN_TOT * G, 256, 0, stream>>>(sampled, params, h2);
  k_transpose<<<dim3(D / 64, GT / 64), 256, 0, stream>>>(op_w, wT, GT, D);
  k_ogemm<<<dim3(BN_PAD / 64, KSPLIT), 256, 0, stream>>>(h2, wT, parts);
  k_final<<<BN_TOT, 256, 0, stream>>>(qf, op_b, parts, ln_g, ln_b, out);
}

// Round 5
// 421.142 us; speedup vs baseline: 2.7911x; 1.1450x over previous
//
#include <hip/hip_runtime.h>
#include <hip/hip_bf16.h>
#include <cstdint>

namespace {

constexpr int B = 4, N = 300, D = 256;
constexpr int G = 4, PIN = 32, POUT = 128;
constexpr int CG = D / G;                    // 64
constexpr int TOTAL = CG * CG + PIN * POUT;  // 8192
constexpr int BN_TOT = B * N;                // 1200
constexpr int BN_PAD = 1216;                 // 19 * 64
constexpr int GT = G * TOTAL;                // 32768

typedef short s16x8 __attribute__((ext_vector_type(8)));   // 8 bf16 = 4 VGPRs
typedef float f32x4 __attribute__((ext_vector_type(4)));

// ---- bf16 helpers (bit-level, RNE) ----
__device__ __forceinline__ float bf2f(unsigned short u) {
  union { unsigned int i; float f; } x; x.i = ((unsigned int)u) << 16; return x.f;
}
__device__ __forceinline__ unsigned short f2bf(float f) {
  union { float f; unsigned int i; } x; x.f = f;
  unsigned int r = x.i + 0x7fffu + ((x.i >> 16) & 1u);
  return (unsigned short)(r >> 16);
}

__device__ __forceinline__ void breduce2(float& a, float& b, volatile float* red) {
  __syncthreads();
  #pragma unroll
  for (int off = 32; off; off >>= 1) {
    a += __shfl_down(a, off, 64);
    b += __shfl_down(b, off, 64);
  }
  int t = threadIdx.x;
  if ((t & 63) == 0) { red[t >> 6] = a; red[4 + (t >> 6)] = b; }
  __syncthreads();
  a = red[0] + red[1] + red[2] + red[3];
  b = red[4] + red[5] + red[6] + red[7];
}

// ---------------- prep: fp32 [R][C] -> bf16 transposed [C][R] ---------------
// mperm=1: within each 8192-column group, the first 4096 output rows get the
// involution local' = (local&63)<<6 | local>>6 — so pgemm emits M transposed.
__global__ __launch_bounds__(256) void k_transpose(
    const float* __restrict__ in, unsigned short* __restrict__ out, int R, int C,
    int mperm) {
  __shared__ unsigned short T[64][72];
  int c0 = blockIdx.x * 64;
  int r0 = blockIdx.y * 64;
  int t = threadIdx.x;
  #pragma unroll
  for (int i = 0; i < 4; ++i) {
    int u = t + i * 256;
    int rr = u >> 4, c4 = (u & 15) * 4;
    float4 v = *(const float4*)(in + (size_t)(r0 + rr) * C + c0 + c4);
    ushort4 w;
    w.x = f2bf(v.x); w.y = f2bf(v.y); w.z = f2bf(v.z); w.w = f2bf(v.w);
    *(ushort4*)&T[rr][c4] = w;
  }
  __syncthreads();
  #pragma unroll
  for (int i = 0; i < 2; ++i) {
    int u = t + i * 256;
    int c = u >> 3, rr8 = (u & 7) * 8;
    unsigned short tmp[8];
    #pragma unroll
    for (int j = 0; j < 8; ++j) tmp[j] = T[rr8 + j][c];
    int n = c0 + c;
    if (mperm) {
      int local = n & 8191;
      if (local < 4096) n = (n & ~8191) | ((local & 63) << 6) | (local >> 6);
    }
    *(uint4*)(out + (size_t)n * R + r0 + rr8) = *(const uint4*)tmp;
  }
}

// ------------- prep: feat fp32 [B][256][HW] -> bf16 [B][HW][256] ------------
__global__ __launch_bounds__(256) void k_featT(
    const float* __restrict__ in, unsigned short* __restrict__ out, int HW) {
  __shared__ unsigned short T[64][72];
  int hw0 = blockIdx.x * 64;
  int d0 = blockIdx.y * 64;
  int bb = blockIdx.z;
  int t = threadIdx.x;
  #pragma unroll
  for (int i = 0; i < 4; ++i) {
    int u = t + i * 256;
    int rr = u >> 4, c4 = (u & 15) * 4;   // rr = channel-in-tile, c4 = pixel
    if (hw0 + c4 + 3 < HW) {
      float4 v = *(const float4*)(in + ((size_t)(bb * D + d0 + rr)) * HW + hw0 + c4);
      ushort4 w;
      w.x = f2bf(v.x); w.y = f2bf(v.y); w.z = f2bf(v.z); w.w = f2bf(v.w);
      *(ushort4*)&T[rr][c4] = w;
    }
  }
  __syncthreads();
  #pragma unroll
  for (int i = 0; i < 2; ++i) {
    int u = t + i * 256;
    int p = u >> 3, dd8 = (u & 7) * 8;    // p = pixel-in-tile, dd8 = channel
    if (hw0 + p < HW) {
      unsigned short tmp[8];
      #pragma unroll
      for (int j = 0; j < 8; ++j) tmp[j] = T[dd8 + j][p];
      *(uint4*)(out + ((size_t)(bb * HW + hw0 + p)) * D + d0 + dd8) = *(const uint4*)tmp;
    }
  }
}

// ---------------- prep: qf fp32 [1200][256] -> bf16 [1216][256] -------------
__global__ __launch_bounds__(256) void k_cvt_qf(
    const float* __restrict__ qf, unsigned short* __restrict__ qb) {
  int e = (blockIdx.x * 256 + threadIdx.x) * 4;
  int row = e >> 8;
  ushort4 w;
  if (row < BN_TOT) {
    float4 v = *(const float4*)(qf + e);
    w.x = f2bf(v.x); w.y = f2bf(v.y); w.z = f2bf(v.z); w.w = f2bf(v.w);
  } else {
    w.x = w.y = w.z = w.w = 0;
  }
  *(ushort4*)(qb + e) = w;
}

// ---------------- kernel 0: offset GEMM (fp32) ------------------------------
__global__ __launch_bounds__(384) void k_off(
    const float* __restrict__ qf, const float* __restrict__ offw,
    const float* __restrict__ offb, float* __restrict__ offsets) {
  int r0 = blockIdx.x * 16;
  int t = threadIdx.x;
  __shared__ float Q[16][256];
  for (int i = t; i < 16 * 256; i += 384)
    Q[i >> 8][i & 255] = qf[(size_t)(r0 + (i >> 8)) * 256 + (i & 255)];
  __syncthreads();
  float acc[16];
  float bias = offb[t];
  #pragma unroll
  for (int r = 0; r < 16; ++r) acc[r] = bias;
  for (int d = 0; d < 256; ++d) {
    float w = offw[(size_t)d * 384 + t];
    #pragma unroll
    for (int r = 0; r < 16; ++r) acc[r] += Q[r][d] * w;
  }
  #pragma unroll
  for (int r = 0; r < 16; ++r) offsets[(size_t)(r0 + r) * 384 + t] = acc[r];
}

// ---------------- kernel 1: bilinear gather, branch-free + deep MLP ---------
__global__ __launch_bounds__(256) void k_gather(
    const float* __restrict__ roi, const float* __restrict__ offsets,
    const unsigned short* __restrict__ featT, unsigned short* __restrict__ sampled) {
  int bn = blockIdx.x;
  int bb = bn / N;
  int t = threadIdx.x;
  __shared__ int   widx[2048];   // [j][l][corner] element offset into featT
  __shared__ float wval[2048];

  const int Wl[4] = {160, 80, 40, 20};
  const int Hl[4] = {100, 50, 25, 13};
  const int loff[4] = {0, 16384000, 20480000, 21504000};
  const int HWl[4] = {16000, 4000, 1000, 260};
  const float sl[4] = {8.f, 16.f, 32.f, 64.f};

  float cx = roi[bn * 4 + 0], cy = roi[bn * 4 + 1];
  float z = roi[bn * 4 + 2], r = roi[bn * 4 + 3];
  float scale = exp2f(z);
  float rwx = scale * exp2f(-0.5f * r);
  float rhy = scale * exp2f(0.5f * r);

  #pragma unroll
  for (int task = t; task < 512; task += 256) {   // task = j*4 + l
    int j = task >> 2, l = task & 3;
    float ox = offsets[(size_t)bn * 384 + j * 3 + 0];
    float oy = offsets[(size_t)bn * 384 + j * 3 + 1];
    float oz = offsets[(size_t)bn * 384 + j * 3 + 2];
    float sx = cx + ox * rwx;
    float sy = cy + oy * rhy;
    float sz = z + oz;
    float lw[4];
    float m = -1e30f;
    #pragma unroll
    for (int ll = 0; ll < 4; ++ll) {
      float dlt = sz - 3.0f - (float)ll;
      lw[ll] = -dlt * dlt * 0.5f;
      m = fmaxf(m, lw[ll]);
    }
    float s = 0.f;
    #pragma unroll
    for (int ll = 0; ll < 4; ++ll) { lw[ll] = expf(lw[ll] - m); s += lw[ll]; }
    float wl_ = lw[l] / s;

    int W = Wl[l], H = Hl[l];
    float px = sx / sl[l] - 0.5f;
    float py = sy / sl[l] - 0.5f;
    float x0f = floorf(px), y0f = floorf(py);
    int x0 = (int)x0f, y0 = (int)y0f;
    float fx = px - x0f, fy = py - y0f;
    int base = loff[l] + bb * HWl[l] * 256;
    #pragma unroll
    for (int k = 0; k < 4; ++k) {
      int xi = x0 + (k & 1), yi = y0 + (k >> 1);
      bool valid = (xi >= 0) & (xi < W) & (yi >= 0) & (yi < H);
      int xc = min(max(xi, 0), W - 1), yc = min(max(yi, 0), H - 1);
      float wgt = ((k & 1) ? fx : 1.f - fx) * ((k >> 1) ? fy : 1.f - fy) * wl_;
      widx[j * 16 + l * 4 + k] = base + (yc * W + xc) * 256;
      wval[j * 16 + l * 4 + k] = valid ? wgt : 0.f;
    }
  }
  __syncthreads();

  int wave = t >> 6, lane = t & 63;
  int half = lane >> 5, ln = lane & 31;
  const unsigned short* fb = featT + wave * 64 + ln * 2;
  #pragma unroll 2
  for (int it = 0; it < 16; ++it) {
    int p = it * 2 + half;
    int j = wave * 32 + p;
    int ix[16]; float w[16]; unsigned int u[16];
    #pragma unroll
    for (int k = 0; k < 16; ++k) { ix[k] = widx[j * 16 + k]; w[k] = wval[j * 16 + k]; }
    #pragma unroll
    for (int k = 0; k < 16; ++k) u[k] = *(const unsigned int*)(fb + ix[k]);
    float a0 = 0.f, a1 = 0.f;
    #pragma unroll
    for (int k = 0; k < 16; ++k) {
      a0 += w[k] * bf2f((unsigned short)(u[k] & 0xffffu));
      a1 += w[k] * bf2f((unsigned short)(u[k] >> 16));
    }
    unsigned int packed = (unsigned int)f2bf(a0) | ((unsigned int)f2bf(a1) << 16);
    *(unsigned int*)(sampled + (((size_t)bn * G + wave) * PIN + p) * CG + ln * 2) = packed;
  }
}

// ---------------- kernel 2: params GEMM via MFMA ----------------------------
__global__ __launch_bounds__(256) void k_pgemm(
    const unsigned short* __restrict__ A, const unsigned short* __restrict__ Bt,
    const float* __restrict__ pgb, unsigned short* __restrict__ params) {
  __shared__ unsigned short As[64][72];
  __shared__ unsigned short Bs[128][72];
  int col0 = blockIdx.x * 128;
  int row0 = blockIdx.y * 64;
  int t = threadIdx.x;
  int wave = t >> 6, lane = t & 63, lr = lane & 15, q = lane >> 4;
  f32x4 acc[4][2] = {};
  for (int k0 = 0; k0 < D; k0 += 64) {
    #pragma unroll
    for (int i = 0; i < 2; ++i) {
      int u = t + i * 256;
      int r = u >> 3, kk = (u & 7) * 8;
      *(uint4*)&As[r][kk] = *(const uint4*)(A + (size_t)(row0 + r) * D + k0 + kk);
    }
    #pragma unroll
    for (int i = 0; i < 4; ++i) {
      int u = t + i * 256;
      int n = u >> 3, kk = (u & 7) * 8;
      *(uint4*)&Bs[n][kk] = *(const uint4*)(Bt + (size_t)(col0 + n) * D + k0 + kk);
    }
    __syncthreads();
    #pragma unroll
    for (int ks = 0; ks < 64; ks += 32) {
      s16x8 af[4], bf[2];
      #pragma unroll
      for (int mi = 0; mi < 4; ++mi)
        af[mi] = *(const s16x8*)&As[mi * 16 + lr][ks + q * 8];
      #pragma unroll
      for (int ni = 0; ni < 2; ++ni)
        bf[ni] = *(const s16x8*)&Bs[wave * 32 + ni * 16 + lr][ks + q * 8];
      #pragma unroll
      for (int mi = 0; mi < 4; ++mi)
        #pragma unroll
        for (int ni = 0; ni < 2; ++ni)
          acc[mi][ni] = __builtin_amdgcn_mfma_f32_16x16x32_bf16(af[mi], bf[ni], acc[mi][ni], 0, 0, 0);
    }
    __syncthreads();
  }
  #pragma unroll
  for (int ni = 0; ni < 2; ++ni) {
    int c = col0 + wave * 32 + ni * 16 + lr;
    // column c holds original column perm(c) (M-region involution) -> its bias
    int local = c & 8191;
    int cb = (local < 4096) ? ((c & ~8191) | ((local & 63) << 6) | (local >> 6)) : c;
    float bias = pgb[cb];
    #pragma unroll
    for (int mi = 0; mi < 4; ++mi) {
      #pragma unroll
      for (int rg = 0; rg < 4; ++rg) {
        int rr = row0 + mi * 16 + q * 4 + rg;
        if (rr < BN_TOT) params[(size_t)rr * GT + c] = f2bf(acc[mi][ni][rg] + bias);
      }
    }
  }
}

// ---------------- kernel 3: per-(b,n,g) mixing via MFMA ---------------------
// block = (bn,g), 4 waves. params M-region stores Mt[d][c] (pre-permuted).
// h1: wave w -> n-tile d=w*16..+15, m = 32 rows, K=64.  LN2+relu -> Ht[d][p].
// h2: wave w -> rows o=w*32..+31, n = 64 cols, K=32 (A = S from params).
__global__ __launch_bounds__(256) void k_mixing(
    const unsigned short* __restrict__ sampled,
    const unsigned short* __restrict__ params,
    unsigned short* __restrict__ h2out) {
  int blk = blockIdx.x;
  int g = blk & 3, bn = blk >> 2;
  const unsigned short* P = params + (size_t)bn * GT + (size_t)g * TOTAL;
  const unsigned short* Sp = sampled + (((size_t)bn * G + g) * PIN) * CG;
  __shared__ unsigned short Ht[64][40];   // h1^T, rows 80 B (16B-aligned)
  __shared__ float red[8];
  int t = threadIdx.x;
  int w = t >> 6, lane = t & 63, lr = lane & 15, q = lane >> 4;

  // ---- h1 = sampled(32x64) @ M(64x64) ----
  f32x4 acc1[2] = {};
  #pragma unroll
  for (int ks = 0; ks < 2; ++ks) {
    s16x8 b = *(const s16x8*)(P + (w * 16 + lr) * 64 + ks * 32 + q * 8);  // Mt[d][c]
    #pragma unroll
    for (int mt = 0; mt < 2; ++mt) {
      s16x8 a = *(const s16x8*)(Sp + (mt * 16 + lr) * 64 + ks * 32 + q * 8);
      acc1[mt] = __builtin_amdgcn_mfma_f32_16x16x32_bf16(a, b, acc1[mt], 0, 0, 0);
    }
  }
  float s1 = 0.f, ss1 = 0.f;
  #pragma unroll
  for (int mt = 0; mt < 2; ++mt)
    #pragma unroll
    for (int rg = 0; rg < 4; ++rg) { float v = acc1[mt][rg]; s1 += v; ss1 += v * v; }
  breduce2(s1, ss1, red);
  {
    float mu = s1 * (1.f / 2048.f);
    float var = ss1 * (1.f / 2048.f) - mu * mu;
    float rs = rsqrtf(var + 1e-5f);
    #pragma unroll
    for (int mt = 0; mt < 2; ++mt) {
      unsigned short pk[4];
      #pragma unroll
      for (int rg = 0; rg < 4; ++rg) {
        float v = (acc1[mt][rg] - mu) * rs;
        pk[rg] = f2bf(v > 0.f ? v : 0.f);
      }
      // C-layout elem (p = mt*16 + q*4 + rg, d = w*16 + lr) -> Ht[d][p]
      *(uint2*)&Ht[w * 16 + lr][mt * 16 + q * 4] = *(const uint2*)pk;
    }
  }
  __syncthreads();

  // ---- h2 = S(128x32) @ h1(32x64) ----
  f32x4 acc2[2][4] = {};
  #pragma unroll
  for (int mt = 0; mt < 2; ++mt) {
    int o = w * 32 + mt * 16 + lr;
    s16x8 a = *(const s16x8*)(P + 4096 + o * 32 + q * 8);   // S[o][p]
    #pragma unroll
    for (int nt = 0; nt < 4; ++nt) {
      s16x8 b = *(const s16x8*)&Ht[nt * 16 + lr][q * 8];    // h1^T[d][p]
      acc2[mt][nt] = __builtin_amdgcn_mfma_f32_16x16x32_bf16(a, b, acc2[mt][nt], 0, 0, 0);
    }
  }
  float s2 = 0.f, ss2 = 0.f;
  #pragma unroll
  for (int mt = 0; mt < 2; ++mt)
    #pragma unroll
    for (int nt = 0; nt < 4; ++nt)
      #pragma unroll
      for (int rg = 0; rg < 4; ++rg) { float v = acc2[mt][nt][rg]; s2 += v; ss2 += v * v; }
  breduce2(s2, ss2, red);
  {
    float mu = s2 * (1.f / 8192.f);
    float var = ss2 * (1.f / 8192.f) - mu * mu;
    float rs = rsqrtf(var + 1e-5f);
    unsigned short* dst = h2out + (size_t)bn * GT + (size_t)g * TOTAL;
    #pragma unroll
    for (int mt = 0; mt < 2; ++mt) {
      #pragma unroll
      for (int nt = 0; nt < 4; ++nt) {
        int d = nt * 16 + lr;
        #pragma unroll
        for (int rg = 0; rg < 4; ++rg) {
          int o = w * 32 + mt * 16 + q * 4 + rg;
          float v = (acc2[mt][nt][rg] - mu) * rs;
          dst[o * 64 + d] = f2bf(v > 0.f ? v : 0.f);
        }
      }
    }
  }
}

// ---------------- kernel 4: output GEMM via MFMA (K-split) ------------------
constexpr int KSPLIT = 32, KCH = GT / KSPLIT;  // 1024
__global__ __launch_bounds__(256) void k_ogemm(
    const unsigned short* __restrict__ A, const unsigned short* __restrict__ Bt,
    float* __restrict__ parts) {
  __shared__ unsigned short As[64][72];
  __shared__ unsigned short Bs[256][72];
  int row0 = blockIdx.x * 64;
  int z = blockIdx.y;
  int kbase = z * KCH;
  int t = threadIdx.x;
  int wave = t >> 6, lane = t & 63, lr = lane & 15, q = lane >> 4;
  f32x4 acc[4][4] = {};
  for (int k0 = 0; k0 < KCH; k0 += 64) {
    #pragma unroll
    for (int i = 0; i < 2; ++i) {
      int u = t + i * 256;
      int r = u >> 3, kk = (u & 7) * 8;
      *(uint4*)&As[r][kk] = *(const uint4*)(A + (size_t)(row0 + r) * GT + kbase + k0 + kk);
    }
    #pragma unroll
    for (int i = 0; i < 8; ++i) {
      int u = t + i * 256;
      int n = u >> 3, kk = (u & 7) * 8;
      *(uint4*)&Bs[n][kk] = *(const uint4*)(Bt + (size_t)n * GT + kbase + k0 + kk);
    }
    __syncthreads();
    #pragma unroll
    for (int ks = 0; ks < 64; ks += 32) {
      s16x8 af[4], bf[4];
      #pragma unroll
      for (int mi = 0; mi < 4; ++mi)
        af[mi] = *(const s16x8*)&As[mi * 16 + lr][ks + q * 8];
      #pragma unroll
      for (int ni = 0; ni < 4; ++ni)
        bf[ni] = *(const s16x8*)&Bs[wave * 64 + ni * 16 + lr][ks + q * 8];
      #pragma unroll
      for (int mi = 0; mi < 4; ++mi)
        #pragma unroll
        for (int ni = 0; ni < 4; ++ni)
          acc[mi][ni] = __builtin_amdgcn_mfma_f32_16x16x32_bf16(af[mi], bf[ni], acc[mi][ni], 0, 0, 0);
    }
    __syncthreads();
  }
  #pragma unroll
  for (int mi = 0; mi < 4; ++mi) {
    #pragma unroll
    for (int ni = 0; ni < 4; ++ni) {
      int c = wave * 64 + ni * 16 + lr;
      #pragma unroll
      for (int rg = 0; rg < 4; ++rg) {
        int rr = row0 + mi * 16 + q * 4 + rg;
        if (rr < BN_TOT)
          parts[((size_t)z * BN_PAD + rr) * D + c] = acc[mi][ni][rg];
      }
    }
  }
}

// ---------------- kernel 5: K-split reduce + residual + LN1 ------------------
__global__ __launch_bounds__(256) void k_final(
    const float* __restrict__ qf, const float* __restrict__ opb,
    const float* __restrict__ parts, const float* __restrict__ lng,
    const float* __restrict__ lnb, float* __restrict__ out) {
  int bn = blockIdx.x;
  int d = threadIdx.x;
  float v = qf[(size_t)bn * D + d] + opb[d];
  #pragma unroll
  for (int s = 0; s < KSPLIT; ++s) v += parts[((size_t)s * BN_PAD + bn) * D + d];
  __shared__ float red[8];
  float a = v, b2 = v * v;
  breduce2(a, b2, red);
  float mu = a * (1.f / D);
  float var = b2 * (1.f / D) - mu * mu;
  float rs = rsqrtf(var + 1e-5f);
  out[(size_t)bn * D + d] = (v - mu) * rs * lng[d] + lnb[d];
}

}  // namespace

extern "C" void kernel_launch(void* const* d_in, const int* in_sizes, int n_in,
                              void* d_out, int out_size, void* d_ws, size_t ws_size,
                              hipStream_t stream) {
  const float* f0 = (const float*)d_in[0];
  const float* f1 = (const float*)d_in[1];
  const float* f2 = (const float*)d_in[2];
  const float* f3 = (const float*)d_in[3];
  const float* qf = (const float*)d_in[4];
  const float* roi = (const float*)d_in[5];
  const float* off_w = (const float*)d_in[6];
  const float* off_b = (const float*)d_in[7];
  const float* pg_w = (const float*)d_in[8];
  const float* pg_b = (const float*)d_in[9];
  const float* op_w = (const float*)d_in[10];
  const float* op_b = (const float*)d_in[11];
  const float* ln_g = (const float*)d_in[12];
  const float* ln_b = (const float*)d_in[13];
  float* out = (float*)d_out;

  // workspace layout (bytes):
  //   sampled bf16 : 19,660,800
  //   h2      bf16 : 79,691,776   (featT bf16 43,540,480 aliases this slot)
  //   params  bf16 : 79,691,776   (parts fp32 39,845,888 aliases after mixing)
  //   wT      bf16 : 16,777,216   (pg_wT, then op_wT)
  //   qf_bf16      :    622,592
  //   offsets fp32 :  1,843,200
  //   total ~ 198.3 MB
  char* ws = (char*)d_ws;
  unsigned short* sampled = (unsigned short*)ws;
  unsigned short* h2      = (unsigned short*)(ws + 19660800ULL);
  unsigned short* featT   = h2;  // alias
  unsigned short* params  = (unsigned short*)(ws + 19660800ULL + 79691776ULL);
  float*          parts   = (float*)(ws + 19660800ULL + 79691776ULL);  // alias
  unsigned short* wT      = (unsigned short*)(ws + 19660800ULL + 2 * 79691776ULL);
  unsigned short* qfb     = (unsigned short*)(ws + 19660800ULL + 2 * 79691776ULL + 16777216ULL);
  float*          offsets = (float*)(ws + 19660800ULL + 2 * 79691776ULL + 16777216ULL + 622592ULL);

  k_featT<<<dim3(250, 4, B), 256, 0, stream>>>(f0, featT + 0,        16000);
  k_featT<<<dim3( 63, 4, B), 256, 0, stream>>>(f1, featT + 16384000, 4000);
  k_featT<<<dim3( 16, 4, B), 256, 0, stream>>>(f2, featT + 20480000, 1000);
  k_featT<<<dim3(  5, 4, B), 256, 0, stream>>>(f3, featT + 21504000, 260);
  k_off<<<BN_TOT / 16, 384, 0, stream>>>(qf, off_w, off_b, offsets);
  // pg_wT with M-region row involution (so pgemm emits M transposed)
  k_transpose<<<dim3(GT / 64, D / 64), 256, 0, stream>>>(pg_w, wT, D, GT, 1);
  k_cvt_qf<<<BN_PAD * D / 1024, 256, 0, stream>>>(qf, qfb);
  k_gather<<<BN_TOT, 256, 0, stream>>>(roi, offsets, featT, sampled);
  k_pgemm<<<dim3(GT / 128, BN_PAD / 64), 256, 0, stream>>>(qfb, wT, pg_b, params);
  k_mixing<<<BN_TOT * G, 256, 0, stream>>>(sampled, params, h2);
  k_transpose<<<dim3(D / 64, GT / 64), 256, 0, stream>>>(op_w, wT, GT, D, 0);
  k_ogemm<<<dim3(BN_PAD / 64, KSPLIT), 256, 0, stream>>>(h2, wT, parts);
  k_final<<<BN_TOT, 256, 0, stream>>>(qf, op_b, parts, ln_g, ln_b, out);
}